// Round 10
// baseline (345.905 us; speedup 1.0000x reference)
//
#include <hip/hip_runtime.h>
#include <cstdint>

#define SEQ     3120
#define SPAD    3200
#define DIM     1536
#define NQKV    4608
#define HEADS   12
#define HD      128
#define SPATIAL 390
#define EPSV    1e-5f
#define KVBLK   64
#define NTILES  49
#define NEGBIG  (-1e30f)
// 1/sqrt(128) * log2(e): attention scores computed in log2 domain.
// FIXED-scale softmax (no running max): |s| <= ~12 in log2 domain, so
// exp2(s) <= 4096 and sum <= ~1e7 -- safely inside fp32; softmax is exactly
// scale-invariant, and bf16 relative precision is scale-free.
#define QSCALE  (0.08838834764831845f * 1.4426950408889634f)
#define CROW(r, hi) ((((r) & 3) + 8 * ((r) >> 2)) + 4 * (hi))

typedef unsigned short u16;
typedef short s16x8 __attribute__((ext_vector_type(8)));
typedef float f32x4 __attribute__((ext_vector_type(4)));
typedef float f32x16 __attribute__((ext_vector_type(16)));

__device__ __forceinline__ u16 f2bf(float f) {
  union { float f; unsigned u; } v; v.f = f;
  unsigned r = v.u + 0x7FFFu + ((v.u >> 16) & 1u);
  return (u16)(r >> 16);
}
__device__ __forceinline__ float bf2f(u16 b) {
  union { unsigned u; float f; } v; v.u = ((unsigned)b) << 16;
  return v.f;
}
__device__ __forceinline__ unsigned cvtpk(float lo, float hi) {
  unsigned r;
  asm("v_cvt_pk_bf16_f32 %0, %1, %2" : "=v"(r) : "v"(lo), "v"(hi));
  return r;
}
// async global->LDS, 16B per lane. LDS dest = wave-uniform base + lane*16.
__device__ __forceinline__ void gload16(const void* g, const void* l) {
  __builtin_amdgcn_global_load_lds(
      (const __attribute__((address_space(1))) unsigned*)g,
      (__attribute__((address_space(3))) unsigned*)(uintptr_t)l,
      16, 0, 0);
}

// ------- 1. convert x fp32 -> bf16 (pad [SEQ,SPAD) rows with 0) + biascat --
__global__ __launch_bounds__(256) void k_convert_x(
    const float* __restrict__ x, const float* __restrict__ bq,
    const float* __restrict__ bk, const float* __restrict__ bv,
    u16* __restrict__ xb, float* __restrict__ bcat) {
  if (blockIdx.x == 0) {
    for (int j = threadIdx.x; j < NQKV; j += 256)
      bcat[j] = (j < DIM) ? bq[j] : (j < 2 * DIM) ? bk[j - DIM] : bv[j - 2 * DIM];
  }
  const int i = (blockIdx.x * 256 + threadIdx.x) * 4;
  if (i >= SPAD * DIM) return;
  const int row = i / DIM;
  float4 v = make_float4(0.f, 0.f, 0.f, 0.f);
  if (row < SEQ) v = *(const float4*)(x + i);
  const unsigned lo = (unsigned)f2bf(v.x) | ((unsigned)f2bf(v.y) << 16);
  const unsigned hi = (unsigned)f2bf(v.z) | ((unsigned)f2bf(v.w) << 16);
  *(uint2*)(xb + i) = make_uint2(lo, hi);
}

// ---------------- 2. transpose+convert weights: Wt[n][k] = W[k][n] ---------
__global__ __launch_bounds__(256) void k_transpose_w(
    const float* __restrict__ Wq, const float* __restrict__ Wk,
    const float* __restrict__ Wv, const float* __restrict__ Wo,
    u16* __restrict__ WtAll, u16* __restrict__ WoT) {
  const int wsel = blockIdx.z;
  const float* W = (wsel == 0) ? Wq : (wsel == 1) ? Wk : (wsel == 2) ? Wv : Wo;
  __shared__ float t[32][33];
  const int k0 = blockIdx.x * 32, n0 = blockIdx.y * 32;
  const int c = threadIdx.x & 31, r8 = threadIdx.x >> 5;
#pragma unroll
  for (int rr = 0; rr < 32; rr += 8)
    t[r8 + rr][c] = W[(size_t)(k0 + r8 + rr) * DIM + n0 + c];
  __syncthreads();
  u16* Wt = (wsel < 3) ? (WtAll + (size_t)wsel * DIM * DIM) : WoT;
#pragma unroll
  for (int rr = 0; rr < 32; rr += 8)
    Wt[(size_t)(n0 + r8 + rr) * DIM + k0 + c] = f2bf(t[c][r8 + rr]);
}

// ---------------- 4/8. bf16 MFMA GEMM: C[m][n] = sum_k A[m][k]*Bt[n][k]+bias
template <int OUT_BF16>
__global__ __launch_bounds__(256) void k_gemm(const u16* __restrict__ A,
                                              const u16* __restrict__ Bt,
                                              const float* __restrict__ bias,
                                              void* __restrict__ Cout,
                                              int N, int K, int storeMmax) {
  __shared__ short As[4096];  // [128][32]
  __shared__ short Bs[4096];  // [128][32]
  const int tid = threadIdx.x;
  const int lane = tid & 63, wv = tid >> 6;
  const int l15 = lane & 15, g = lane >> 4;
  const int brow = blockIdx.y * 128, bcol = blockIdx.x * 128;
  const int wr = wv >> 1, wc = wv & 1;

  const f32x4 z4 = {0.f, 0.f, 0.f, 0.f};
  f32x4 acc[4][4];
#pragma unroll
  for (int m = 0; m < 4; ++m)
#pragma unroll
    for (int n = 0; n < 4; ++n) acc[m][n] = z4;

  const int srow = wv * 16 + (lane >> 2);
  const int skk = (lane & 3) * 8;
  const u16* Ab = A + (size_t)(brow + srow) * K + skk;
  const u16* Bb = Bt + (size_t)(bcol + srow) * K + skk;
  short* AsW = As + wv * 512;
  short* BsW = Bs + wv * 512;
  const size_t step64 = (size_t)64 * K;

  for (int k0 = 0; k0 < K; k0 += 32) {
    __syncthreads();
    gload16(Ab + k0, AsW);
    gload16(Ab + k0 + step64, AsW + 2048);
    gload16(Bb + k0, BsW);
    gload16(Bb + k0 + step64, BsW + 2048);
    __syncthreads();
    s16x8 a[4], b[4];
#pragma unroll
    for (int m = 0; m < 4; ++m)
      a[m] = *(const s16x8*)&As[(wr * 64 + m * 16 + l15) * 32 + g * 8];
#pragma unroll
    for (int n = 0; n < 4; ++n)
      b[n] = *(const s16x8*)&Bs[(wc * 64 + n * 16 + l15) * 32 + g * 8];
#pragma unroll
    for (int m = 0; m < 4; ++m)
#pragma unroll
      for (int n = 0; n < 4; ++n)
        acc[m][n] = __builtin_amdgcn_mfma_f32_16x16x32_bf16(a[m], b[n], acc[m][n], 0, 0, 0);
  }

#pragma unroll
  for (int m = 0; m < 4; ++m) {
#pragma unroll
    for (int n = 0; n < 4; ++n) {
      const int cc = bcol + wc * 64 + n * 16 + l15;
      const float bb = bias[cc];
#pragma unroll
      for (int i = 0; i < 4; ++i) {
        const int r = brow + wr * 64 + m * 16 + g * 4 + i;
        if (r < storeMmax) {
          const float v = acc[m][n][i] + bb;
          if (OUT_BF16) ((u16*)Cout)[(size_t)r * N + cc] = f2bf(v);
          else          ((float*)Cout)[(size_t)r * N + cc] = v;
        }
      }
    }
  }
}

// ---------------- 5. per-token: rmsnorm + rope + biases --------------------
__global__ __launch_bounds__(256) void k_post(
    const u16* __restrict__ Pqkv, const float* __restrict__ freqs,
    const float* __restrict__ gq, const float* __restrict__ gk,
    const float* __restrict__ qkfb, const float* __restrict__ vfb,
    const float* __restrict__ vsb,
    u16* __restrict__ Qf, u16* __restrict__ Kf, u16* __restrict__ Vf) {
  const int s = blockIdx.x;
  const int t = threadIdx.x;
  const int fidx = s / SPATIAL;
  const int sp = s - fidx * SPATIAL;
  __shared__ float cs[64], sn[64];
  __shared__ float red[8];
  if (t < 64) {
    const float a = freqs[s * 64 + t];
    cs[t] = __cosf(a);
    sn[t] = __sinf(a);
  }
  const u16* qrow = Pqkv + (size_t)s * NQKV;
  const u16* krow = qrow + DIM;
  const u16* vrow = qrow + 2 * DIM;
  float sq = 0.f, sk = 0.f;
  for (int i = t; i < DIM; i += 256) {
    const float a = bf2f(qrow[i]); sq += a * a;
    const float b = bf2f(krow[i]); sk += b * b;
  }
#pragma unroll
  for (int off = 1; off < 64; off <<= 1) {
    sq += __shfl_xor(sq, off);
    sk += __shfl_xor(sk, off);
  }
  const int lane = t & 63, wv = t >> 6;
  if (lane == 0) { red[wv] = sq; red[wv + 4] = sk; }
  __syncthreads();
  sq = red[0] + red[1] + red[2] + red[3];
  sk = red[4] + red[5] + red[6] + red[7];
  const float rq = rsqrtf(sq * (1.0f / DIM) + EPSV);
  const float rk = rsqrtf(sk * (1.0f / DIM) + EPSV);
  for (int p = t; p < 768; p += 256) {
    const int d = 2 * p;
    const int pin = p & 63;
    const float c = cs[pin], s_ = sn[pin];
    const float bq0 = qkfb[fidx * DIM + d], bq1 = qkfb[fidx * DIM + d + 1];
    float xr = bf2f(qrow[d]) * rq * gq[d];
    float xi = bf2f(qrow[d + 1]) * rq * gq[d + 1];
    const float q0 = (xr * c - xi * s_ + bq0) * QSCALE;
    const float q1 = (xr * s_ + xi * c + bq1) * QSCALE;
    *(unsigned*)&Qf[(size_t)s * DIM + d] = (unsigned)f2bf(q0) | ((unsigned)f2bf(q1) << 16);
    xr = bf2f(krow[d]) * rk * gk[d];
    xi = bf2f(krow[d + 1]) * rk * gk[d + 1];
    const float k0 = xr * c - xi * s_ + bq0;
    const float k1 = xr * s_ + xi * c + bq1;
    *(unsigned*)&Kf[(size_t)s * DIM + d] = (unsigned)f2bf(k0) | ((unsigned)f2bf(k1) << 16);
    const float v0 = bf2f(vrow[d]) + vfb[fidx * DIM + d] + vsb[(size_t)sp * DIM + d];
    const float v1 = bf2f(vrow[d + 1]) + vfb[fidx * DIM + d + 1] + vsb[(size_t)sp * DIM + d + 1];
    *(unsigned*)&Vf[(size_t)s * DIM + d] = (unsigned)f2bf(v0) | ((unsigned)f2bf(v1) << 16);
  }
}

// ---------------- 6. V transpose: Vf[s][1536] -> Vt[dglob][SPAD] -----------
__global__ __launch_bounds__(256) void k_transpose_v(const u16* __restrict__ Vf,
                                                     u16* __restrict__ Vt) {
  __shared__ u16 tile[64][65];
  const int s0 = blockIdx.x * 64, c0 = blockIdx.y * 64;
  const int c = threadIdx.x & 63, r4 = threadIdx.x >> 6;
#pragma unroll
  for (int rr = 0; rr < 64; rr += 4) {
    const int s = s0 + r4 + rr;
    tile[r4 + rr][c] = (s < SEQ) ? Vf[(size_t)s * DIM + c0 + c] : (u16)0;
  }
  __syncthreads();
#pragma unroll
  for (int rr = 0; rr < 64; rr += 4) {
    const int dglob = c0 + r4 + rr;
    Vt[(size_t)dglob * SPAD + s0 + c] = tile[c][r4 + rr];
  }
}

// ---------------- 7. flash attention: R8 math, co-residency re-shard -------
// grid (50, 12) = 600 blocks > 256 CUs, 128 threads = 2 warps, LDS 64 KB ->
// 2 blocks/CU co-reside (grid 240 < 256 never could: that was R3-R8's 1-block
// convoy). Per-tile math/layouts byte-identical to R8; KVBLK stays 64.
// Warp w owns q rows bx*64+w*32..+31; lane owns q-row l&31 (partner lane^32).
// K LDS [64 key][16 ch][8] ch^=key&15; V^T LDS [128 d][8 ch][8] ch^=d&7.
// Both warps stage 16 gload16/tile; FIXED-scale softmax (see QSCALE note).
__global__ __launch_bounds__(128, 2) void k_attn(const u16* __restrict__ Qf,
                                                 const u16* __restrict__ Kf,
                                                 const u16* __restrict__ Vt,
                                                 u16* __restrict__ AttO) {
  __shared__ short Ks[2][8192];  // [64 key][16 chunk][8]
  __shared__ short Vs[2][8192];  // [128 d][8 chunk][8]
  const int h = blockIdx.y;
  const int tid = threadIdx.x;
  const int lane = tid & 63, w = tid >> 6;     // w in 0..1
  const int l31 = lane & 31, hi = lane >> 5;
  const int qrow = blockIdx.x * 64 + w * 32 + l31;

  // Q B-frags: qb[s] = Q[qrow][16s + 8hi + j]
  s16x8 qb[8];
  {
    const u16* qp = Qf + (size_t)qrow * DIM + h * HD + hi * 8;
#pragma unroll
    for (int s = 0; s < 8; ++s) qb[s] = *(const s16x8*)(qp + s * 16);
  }

  f32x16 o[4];
#pragma unroll
  for (int d = 0; d < 4; ++d)
#pragma unroll
    for (int r = 0; r < 16; ++r) o[d][r] = 0.f;
  float sl = 0.f;

  // staging pointers: 8 K-loads + 8 V-loads per warp per tile
  const u16* Kp[8];
  const u16* Vp[8];
#pragma unroll
  for (int it = 0; it < 8; ++it) {
    const int krow = w * 32 + it * 4 + (lane >> 4);          // 0..63
    const int kch = (lane & 15) ^ (krow & 15);
    Kp[it] = Kf + (size_t)krow * DIM + h * HD + kch * 8;
    const int vrow = w * 64 + it * 8 + (lane >> 3);          // d: 0..127
    const int vch = (lane & 7) ^ (lane >> 3);                // ^ (vrow&7)
    Vp[it] = Vt + (size_t)(h * HD + vrow) * SPAD + vch * 8;
  }
  auto stage = [&](int T, int B) {
    const size_t kof = (size_t)T * KVBLK * DIM;
    const int vof = T * KVBLK;
#pragma unroll
    for (int it = 0; it < 8; ++it) {
      gload16(Kp[it] + kof, &Ks[B][(w * 32 + it * 4) * 128]);
      gload16(Vp[it] + vof, &Vs[B][(w * 64 + it * 8) * 64]);
    }
  };

  asm volatile("s_waitcnt vmcnt(0)" ::: "memory");  // drain qb loads
  stage(0, 0);

  for (int t = 0; t < NTILES; ++t) {
    const int b = t & 1;
    if (t + 1 < NTILES) {
      stage(t + 1, b ^ 1);
      asm volatile("s_waitcnt vmcnt(16)" ::: "memory");  // tile t's 16 done
    } else {
      asm volatile("s_waitcnt vmcnt(0)" ::: "memory");
    }
    __builtin_amdgcn_s_barrier();
    __builtin_amdgcn_sched_barrier(0);

    // S^T = K Q  (D[key][q]: col q = l31, row key = CROW(r,hi) per grp of 32)
    f32x16 st[2];
#pragma unroll
    for (int r = 0; r < 16; ++r) { st[0][r] = 0.f; st[1][r] = 0.f; }
    __builtin_amdgcn_s_setprio(1);
#pragma unroll
    for (int grp = 0; grp < 2; ++grp)
#pragma unroll
      for (int s = 0; s < 8; ++s) {
        const s16x8 ka = *(const s16x8*)&Ks[b][(grp * 32 + l31) * 128 +
                                              (((2 * s + hi) ^ (lane & 15)) * 8)];
        st[grp] = __builtin_amdgcn_mfma_f32_32x32x16_bf16(ka, qb[s], st[grp], 0, 0, 0);
      }
    __builtin_amdgcn_s_setprio(0);

    // hoist V B-frags (ds_read latency hides under softmax VALU)
    s16x8 vb[4][4];
#pragma unroll
    for (int s = 0; s < 4; ++s)
#pragma unroll
      for (int d = 0; d < 4; ++d)
        vb[s][d] = *(const s16x8*)&Vs[b][(d * 32 + l31) * 64 +
                                         (((2 * s + hi) ^ (lane & 7)) * 8)];

    if (t == NTILES - 1) {  // keys 3120..3135 invalid: grp1 regs 8..15
#pragma unroll
      for (int r = 8; r < 16; ++r) st[1][r] = NEGBIG;  // exp2 -> 0
    }
    // P = exp2(S): fixed scale, lane-local sums, pack bf16, partner exchange
    unsigned W[16], X[16];
    float p0s = 0.f, p1s = 0.f, p2s = 0.f, p3s = 0.f;
#pragma unroll
    for (int grp = 0; grp < 2; ++grp)
#pragma unroll
      for (int i = 0; i < 8; ++i) {
        const float p0 = exp2f(st[grp][2 * i]);
        const float p1 = exp2f(st[grp][2 * i + 1]);
        if (grp) { p2s += p0; p3s += p1; } else { p0s += p0; p1s += p1; }
        W[grp * 8 + i] = cvtpk(p0, p1);
      }
    sl += (p0s + p1s) + (p2s + p3s);
#pragma unroll
    for (int j = 0; j < 16; ++j) X[j] = __shfl_xor((int)W[j], 32);

    // O += P V
    __builtin_amdgcn_s_setprio(1);
#pragma unroll
    for (int s = 0; s < 4; ++s) {
      const int base = (s >> 1) * 8 + (s & 1) * 4;
      unsigned pw[4];
      pw[0] = hi ? X[base + 2] : W[base + 0];
      pw[1] = hi ? X[base + 3] : W[base + 1];
      pw[2] = hi ? W[base + 2] : X[base + 0];
      pw[3] = hi ? W[base + 3] : X[base + 1];
      const s16x8 pa = *(const s16x8*)pw;
#pragma unroll
      for (int d = 0; d < 4; ++d)
        o[d] = __builtin_amdgcn_mfma_f32_32x32x16_bf16(pa, vb[s][d], o[d], 0, 0, 0);
    }
    __builtin_amdgcn_s_setprio(0);
    __builtin_amdgcn_s_barrier();
    __builtin_amdgcn_sched_barrier(0);
  }

  sl += __shfl_xor(sl, 32);
  const float rs = 1.0f / sl;
#pragma unroll
  for (int r = 0; r < 16; ++r) {
    const float rq = __shfl(rs, CROW(r, hi));
    const int row = blockIdx.x * 64 + w * 32 + CROW(r, hi);
    if (row < SEQ) {
#pragma unroll
      for (int d = 0; d < 4; ++d)
        AttO[(size_t)row * DIM + h * HD + d * 32 + l31] = f2bf(o[d][r] * rq);
    }
  }
}

// ---------------------------------------------------------------------------
extern "C" void kernel_launch(void* const* d_in, const int* in_sizes, int n_in,
                              void* d_out, int out_size, void* d_ws, size_t ws_size,
                              hipStream_t stream) {
  const float* x    = (const float*)d_in[0];
  const float* freqs= (const float*)d_in[1];
  const float* Wq   = (const float*)d_in[2];
  const float* bq   = (const float*)d_in[3];
  const float* gq   = (const float*)d_in[4];
  const float* Wk   = (const float*)d_in[5];
  const float* bk   = (const float*)d_in[6];
  const float* gk   = (const float*)d_in[7];
  const float* Wv   = (const float*)d_in[8];
  const float* bv   = (const float*)d_in[9];
  const float* Wo   = (const float*)d_in[10];
  const float* bo   = (const float*)d_in[11];
  const float* qkfb = (const float*)d_in[12];
  const float* vfb  = (const float*)d_in[13];
  const float* vsb  = (const float*)d_in[14];

  if (ws_size < (size_t)87705600) return;

  char* ws = (char*)d_ws;
  u16*   xb    = (u16*)(ws);               // [3200][1536] bf16
  u16*   Vt    = (u16*)(ws);               // alias: xb dead after QKV GEMM
  u16*   WtAll = (u16*)(ws + 9830400);     // [4608][1536] bf16 (Wq|Wk|Wv)^T
  u16*   WoT   = (u16*)(ws + 23986176);    // [1536][1536] bf16 Wo^T
  float* bcat  = (float*)(ws + 28704768);  // [4608]
  u16*   Pqkv  = (u16*)(ws + 28723200);    // [3200][4608] bf16
  u16*   AttO  = (u16*)(ws + 28723200);    // alias: Pqkv dead after k_post
  u16*   Qf    = (u16*)(ws + 58214400);    // [3200][1536] bf16
  u16*   Kf    = (u16*)(ws + 68044800);    // [3200][1536] bf16
  u16*   Vf    = (u16*)(ws + 77875200);    // [3200][1536] bf16

  k_convert_x<<<4800, 256, 0, stream>>>(x, bq, bk, bv, xb, bcat);
  k_transpose_w<<<dim3(48, 48, 4), 256, 0, stream>>>(Wq, Wk, Wv, Wo, WtAll, WoT);
  k_gemm<1><<<dim3(36, 25), 256, 0, stream>>>(xb, WtAll, bcat, Pqkv, NQKV, DIM, SPAD);
  k_post<<<SEQ, 256, 0, stream>>>(Pqkv, freqs, gq, gk, qkfb, vfb, vsb, Qf, Kf, Vf);
  k_transpose_v<<<dim3(50, 24), 256, 0, stream>>>(Vf, Vt);
  k_attn<<<dim3(50, 12), 128, 0, stream>>>(Qf, Kf, Vt, AttO);
  k_gemm<0><<<dim3(12, 25), 256, 0, stream>>>(AttO, WoT, bo, d_out, DIM, DIM, SEQ);
}

// Round 11
// 259.504 us; speedup vs baseline: 1.3329x; 1.3329x over previous
//
#include <hip/hip_runtime.h>
#include <cstdint>

#define SEQ     3120
#define SPAD    3200
#define DIM     1536
#define NQKV    4608
#define HEADS   12
#define HD      128
#define SPATIAL 390
#define EPSV    1e-5f
#define KVBLK   64
#define NTILES  49
#define NEGBIG  (-1e30f)
// 1/sqrt(128) * log2(e): attention scores computed in log2 domain.
// FIXED-scale softmax (no running max): |s| <= ~12 in log2 domain, so
// exp2(s) <= 4096 and sum <= ~1e7 -- safely inside fp32; softmax is exactly
// scale-invariant, and bf16 relative precision is scale-free.
#define QSCALE  (0.08838834764831845f * 1.4426950408889634f)
#define CROW(r, hi) ((((r) & 3) + 8 * ((r) >> 2)) + 4 * (hi))

typedef unsigned short u16;
typedef short s16x8 __attribute__((ext_vector_type(8)));
typedef float f32x4 __attribute__((ext_vector_type(4)));
typedef float f32x16 __attribute__((ext_vector_type(16)));

__device__ __forceinline__ u16 f2bf(float f) {
  union { float f; unsigned u; } v; v.f = f;
  unsigned r = v.u + 0x7FFFu + ((v.u >> 16) & 1u);
  return (u16)(r >> 16);
}
__device__ __forceinline__ float bf2f(u16 b) {
  union { unsigned u; float f; } v; v.u = ((unsigned)b) << 16;
  return v.f;
}
__device__ __forceinline__ unsigned cvtpk(float lo, float hi) {
  unsigned r;
  asm("v_cvt_pk_bf16_f32 %0, %1, %2" : "=v"(r) : "v"(lo), "v"(hi));
  return r;
}
// async global->LDS, 16B per lane. LDS dest = wave-uniform base + lane*16.
__device__ __forceinline__ void gload16(const void* g, const void* l) {
  __builtin_amdgcn_global_load_lds(
      (const __attribute__((address_space(1))) unsigned*)g,
      (__attribute__((address_space(3))) unsigned*)(uintptr_t)l,
      16, 0, 0);
}

// ------- 1. convert x fp32 -> bf16 (pad [SEQ,SPAD) rows with 0) + biascat --
__global__ __launch_bounds__(256) void k_convert_x(
    const float* __restrict__ x, const float* __restrict__ bq,
    const float* __restrict__ bk, const float* __restrict__ bv,
    u16* __restrict__ xb, float* __restrict__ bcat) {
  if (blockIdx.x == 0) {
    for (int j = threadIdx.x; j < NQKV; j += 256)
      bcat[j] = (j < DIM) ? bq[j] : (j < 2 * DIM) ? bk[j - DIM] : bv[j - 2 * DIM];
  }
  const int i = (blockIdx.x * 256 + threadIdx.x) * 4;
  if (i >= SPAD * DIM) return;
  const int row = i / DIM;
  float4 v = make_float4(0.f, 0.f, 0.f, 0.f);
  if (row < SEQ) v = *(const float4*)(x + i);
  const unsigned lo = (unsigned)f2bf(v.x) | ((unsigned)f2bf(v.y) << 16);
  const unsigned hi = (unsigned)f2bf(v.z) | ((unsigned)f2bf(v.w) << 16);
  *(uint2*)(xb + i) = make_uint2(lo, hi);
}

// ---------------- 2. transpose+convert weights: Wt[n][k] = W[k][n] ---------
__global__ __launch_bounds__(256) void k_transpose_w(
    const float* __restrict__ Wq, const float* __restrict__ Wk,
    const float* __restrict__ Wv, const float* __restrict__ Wo,
    u16* __restrict__ WtAll, u16* __restrict__ WoT) {
  const int wsel = blockIdx.z;
  const float* W = (wsel == 0) ? Wq : (wsel == 1) ? Wk : (wsel == 2) ? Wv : Wo;
  __shared__ float t[32][33];
  const int k0 = blockIdx.x * 32, n0 = blockIdx.y * 32;
  const int c = threadIdx.x & 31, r8 = threadIdx.x >> 5;
#pragma unroll
  for (int rr = 0; rr < 32; rr += 8)
    t[r8 + rr][c] = W[(size_t)(k0 + r8 + rr) * DIM + n0 + c];
  __syncthreads();
  u16* Wt = (wsel < 3) ? (WtAll + (size_t)wsel * DIM * DIM) : WoT;
#pragma unroll
  for (int rr = 0; rr < 32; rr += 8)
    Wt[(size_t)(n0 + r8 + rr) * DIM + k0 + c] = f2bf(t[c][r8 + rr]);
}

// ------- 4/8. bf16 MFMA GEMM, BK=64, swizzled LDS, XCD-swizzled 1D grid ----
// C[m][n] = sum_k A[m][k]*Bt[n][k] + bias[n]. 128x128 tile, 4 waves (2x2),
// single-buffered BK=64 (24 barrier-drains for K=1536 vs 48 at BK=32).
// LDS tile [128 row][8 ch][8 shorts], ch ^= row&7 (2-way reads, free);
// staged via pre-swizzled global source + linear gload_lds (rule 21).
// Summation order identical to BK=32 version -> bit-identical C.
template <int OUT_BF16>
__global__ __launch_bounds__(256) void k_gemm(const u16* __restrict__ A,
                                              const u16* __restrict__ Bt,
                                              const float* __restrict__ bias,
                                              void* __restrict__ Cout,
                                              int N, int K, int storeMmax,
                                              int nbx) {
  __shared__ short As[8192];  // [128][64] swizzled
  __shared__ short Bs[8192];
  // bijective XCD swizzle (m204): nwg = gridDim.x, 8 XCDs
  const int nwg = gridDim.x;
  const int q = nwg >> 3, r = nwg & 7;
  const int xcd = blockIdx.x & 7, idx = blockIdx.x >> 3;
  const int swz = (xcd < r ? xcd * (q + 1) : r * (q + 1) + (xcd - r) * q) + idx;
  const int bxi = swz % nbx, byi = swz / nbx;
  const int brow = byi * 128, bcol = bxi * 128;

  const int tid = threadIdx.x;
  const int lane = tid & 63, wv = tid >> 6;
  const int l15 = lane & 15, g = lane >> 4;
  const int wr = wv >> 1, wc = wv & 1;

  const f32x4 z4 = {0.f, 0.f, 0.f, 0.f};
  f32x4 acc[4][4];
#pragma unroll
  for (int m = 0; m < 4; ++m)
#pragma unroll
    for (int n = 0; n < 4; ++n) acc[m][n] = z4;

  // staging: 4 gload16/wave each for A and B; lane covers 8 shorts of one row
  const u16* Ap[4];
  const u16* Bp[4];
  const int sch = ((lane & 7) ^ ((lane >> 3) & 7)) * 8;  // pre-swizzled col
#pragma unroll
  for (int it = 0; it < 4; ++it) {
    const int row = it * 32 + wv * 8 + (lane >> 3);
    Ap[it] = A + (size_t)(brow + row) * K + sch;
    Bp[it] = Bt + (size_t)(bcol + row) * K + sch;
  }

  for (int k0 = 0; k0 < K; k0 += 64) {
    __syncthreads();
#pragma unroll
    for (int it = 0; it < 4; ++it) {
      gload16(Ap[it] + k0, As + (it * 32 + wv * 8) * 64);
      gload16(Bp[it] + k0, Bs + (it * 32 + wv * 8) * 64);
    }
    __syncthreads();  // drains vmcnt before barrier (compiler-inserted)
#pragma unroll
    for (int kk = 0; kk < 2; ++kk) {
      s16x8 a[4], b[4];
#pragma unroll
      for (int m = 0; m < 4; ++m)
        a[m] = *(const s16x8*)&As[(wr * 64 + m * 16 + l15) * 64 +
                                  (((kk * 4 + g) ^ (l15 & 7)) * 8)];
#pragma unroll
      for (int n = 0; n < 4; ++n)
        b[n] = *(const s16x8*)&Bs[(wc * 64 + n * 16 + l15) * 64 +
                                  (((kk * 4 + g) ^ (l15 & 7)) * 8)];
#pragma unroll
      for (int m = 0; m < 4; ++m)
#pragma unroll
        for (int n = 0; n < 4; ++n)
          acc[m][n] = __builtin_amdgcn_mfma_f32_16x16x32_bf16(a[m], b[n], acc[m][n], 0, 0, 0);
    }
  }

#pragma unroll
  for (int m = 0; m < 4; ++m) {
#pragma unroll
    for (int n = 0; n < 4; ++n) {
      const int cc = bcol + wc * 64 + n * 16 + l15;
      const float bb = bias[cc];
#pragma unroll
      for (int i = 0; i < 4; ++i) {
        const int rr = brow + wr * 64 + m * 16 + g * 4 + i;
        if (rr < storeMmax) {
          const float v = acc[m][n][i] + bb;
          if (OUT_BF16) ((u16*)Cout)[(size_t)rr * N + cc] = f2bf(v);
          else          ((float*)Cout)[(size_t)rr * N + cc] = v;
        }
      }
    }
  }
}

// ---------------- 5. per-token: rmsnorm + rope + biases --------------------
__global__ __launch_bounds__(256) void k_post(
    const u16* __restrict__ Pqkv, const float* __restrict__ freqs,
    const float* __restrict__ gq, const float* __restrict__ gk,
    const float* __restrict__ qkfb, const float* __restrict__ vfb,
    const float* __restrict__ vsb,
    u16* __restrict__ Qf, u16* __restrict__ Kf, u16* __restrict__ Vf) {
  const int s = blockIdx.x;
  const int t = threadIdx.x;
  const int fidx = s / SPATIAL;
  const int sp = s - fidx * SPATIAL;
  __shared__ float cs[64], sn[64];
  __shared__ float red[8];
  if (t < 64) {
    const float a = freqs[s * 64 + t];
    cs[t] = __cosf(a);
    sn[t] = __sinf(a);
  }
  const u16* qrow = Pqkv + (size_t)s * NQKV;
  const u16* krow = qrow + DIM;
  const u16* vrow = qrow + 2 * DIM;
  float sq = 0.f, sk = 0.f;
  for (int i = t; i < DIM; i += 256) {
    const float a = bf2f(qrow[i]); sq += a * a;
    const float b = bf2f(krow[i]); sk += b * b;
  }
#pragma unroll
  for (int off = 1; off < 64; off <<= 1) {
    sq += __shfl_xor(sq, off);
    sk += __shfl_xor(sk, off);
  }
  const int lane = t & 63, wv = t >> 6;
  if (lane == 0) { red[wv] = sq; red[wv + 4] = sk; }
  __syncthreads();
  sq = red[0] + red[1] + red[2] + red[3];
  sk = red[4] + red[5] + red[6] + red[7];
  const float rq = rsqrtf(sq * (1.0f / DIM) + EPSV);
  const float rk = rsqrtf(sk * (1.0f / DIM) + EPSV);
  for (int p = t; p < 768; p += 256) {
    const int d = 2 * p;
    const int pin = p & 63;
    const float c = cs[pin], s_ = sn[pin];
    const float bq0 = qkfb[fidx * DIM + d], bq1 = qkfb[fidx * DIM + d + 1];
    float xr = bf2f(qrow[d]) * rq * gq[d];
    float xi = bf2f(qrow[d + 1]) * rq * gq[d + 1];
    const float q0 = (xr * c - xi * s_ + bq0) * QSCALE;
    const float q1 = (xr * s_ + xi * c + bq1) * QSCALE;
    *(unsigned*)&Qf[(size_t)s * DIM + d] = (unsigned)f2bf(q0) | ((unsigned)f2bf(q1) << 16);
    xr = bf2f(krow[d]) * rk * gk[d];
    xi = bf2f(krow[d + 1]) * rk * gk[d + 1];
    const float k0 = xr * c - xi * s_ + bq0;
    const float k1 = xr * s_ + xi * c + bq1;
    *(unsigned*)&Kf[(size_t)s * DIM + d] = (unsigned)f2bf(k0) | ((unsigned)f2bf(k1) << 16);
    const float v0 = bf2f(vrow[d]) + vfb[fidx * DIM + d] + vsb[(size_t)sp * DIM + d];
    const float v1 = bf2f(vrow[d + 1]) + vfb[fidx * DIM + d + 1] + vsb[(size_t)sp * DIM + d + 1];
    *(unsigned*)&Vf[(size_t)s * DIM + d] = (unsigned)f2bf(v0) | ((unsigned)f2bf(v1) << 16);
  }
}

// ---------------- 6. V transpose: Vf[s][1536] -> Vt[dglob][SPAD] -----------
__global__ __launch_bounds__(256) void k_transpose_v(const u16* __restrict__ Vf,
                                                     u16* __restrict__ Vt) {
  __shared__ u16 tile[64][65];
  const int s0 = blockIdx.x * 64, c0 = blockIdx.y * 64;
  const int c = threadIdx.x & 63, r4 = threadIdx.x >> 6;
#pragma unroll
  for (int rr = 0; rr < 64; rr += 4) {
    const int s = s0 + r4 + rr;
    tile[r4 + rr][c] = (s < SEQ) ? Vf[(size_t)s * DIM + c0 + c] : (u16)0;
  }
  __syncthreads();
#pragma unroll
  for (int rr = 0; rr < 64; rr += 4) {
    const int dglob = c0 + r4 + rr;
    Vt[(size_t)dglob * SPAD + s0 + c] = tile[c][r4 + rr];
  }
}

// ---------------- 7. flash attention (R8 kernel, verified 121.6us) ---------
// grid (20, 12), 320 threads = 5 warps, 128 VGPR, no spill.
// Warp w owns q rows bx*160+w*32..+31; lane owns q-row l&31 (partner lane^32).
// K LDS [64][128] chunk^=(row&15); V^T LDS [128][64] chunk^=(row&7); staged by
// warps 0-3 via pre-swizzled global source + linear gload_lds.
// FIXED-scale softmax: P = exp2(s) directly (see QSCALE note).
__global__ __launch_bounds__(320, 2) void k_attn(const u16* __restrict__ Qf,
                                                 const u16* __restrict__ Kf,
                                                 const u16* __restrict__ Vt,
                                                 u16* __restrict__ AttO) {
  __shared__ short Ks[2][8192];  // [64 key][16 chunk][8]
  __shared__ short Vs[2][8192];  // [128 d][8 chunk][8]
  const int h = blockIdx.y;
  const int tid = threadIdx.x;
  const int lane = tid & 63, w = tid >> 6;     // w in 0..4
  const int l31 = lane & 31, hi = lane >> 5;
  const int qrow = blockIdx.x * 160 + w * 32 + l31;

  // Q B-frags: qb[s] = Q[qrow][16s + 8hi + j]
  s16x8 qb[8];
  {
    const u16* qp = Qf + (size_t)qrow * DIM + h * HD + hi * 8;
#pragma unroll
    for (int s = 0; s < 8; ++s) qb[s] = *(const s16x8*)(qp + s * 16);
  }

  f32x16 o[4];
#pragma unroll
  for (int d = 0; d < 4; ++d)
#pragma unroll
    for (int r = 0; r < 16; ++r) o[d][r] = 0.f;
  float sl = 0.f;

  // staging pointers (warps 0..3 only)
  const u16* Kp[4];
  const u16* Vp[4];
  if (w < 4) {
#pragma unroll
    for (int it = 0; it < 4; ++it) {
      const int krow = w * 16 + it * 4 + (lane >> 4);
      const int kch = (lane & 15) ^ (it * 4 + (lane >> 4));
      Kp[it] = Kf + (size_t)krow * DIM + h * HD + kch * 8;
      const int vrow = w * 32 + it * 8 + (lane >> 3);
      const int vch = (lane & 7) ^ (lane >> 3);
      Vp[it] = Vt + (size_t)(h * HD + vrow) * SPAD + vch * 8;
    }
  }
  auto stage = [&](int T, int B) {
    const size_t kof = (size_t)T * KVBLK * DIM;
    const int vof = T * KVBLK;
#pragma unroll
    for (int it = 0; it < 4; ++it) {
      gload16(Kp[it] + kof, &Ks[B][(w * 16 + it * 4) * 128]);
      gload16(Vp[it] + vof, &Vs[B][(w * 32 + it * 8) * 64]);
    }
  };

  if (w < 4) {
    asm volatile("s_waitcnt vmcnt(0)" ::: "memory");
    stage(0, 0);
  }

  for (int t = 0; t < NTILES; ++t) {
    const int b = t & 1;
    if (w < 4) {
      if (t + 1 < NTILES) {
        stage(t + 1, b ^ 1);
        asm volatile("s_waitcnt vmcnt(8)" ::: "memory");
      } else {
        asm volatile("s_waitcnt vmcnt(0)" ::: "memory");
      }
    }
    __builtin_amdgcn_s_barrier();
    __builtin_amdgcn_sched_barrier(0);

    // S^T = K Q  (D[key][q]: col q = l31, row key = CROW(r,hi) per grp of 32)
    f32x16 st[2];
#pragma unroll
    for (int r = 0; r < 16; ++r) { st[0][r] = 0.f; st[1][r] = 0.f; }
    __builtin_amdgcn_s_setprio(1);
#pragma unroll
    for (int grp = 0; grp < 2; ++grp)
#pragma unroll
      for (int s = 0; s < 8; ++s) {
        const s16x8 ka = *(const s16x8*)&Ks[b][(grp * 32 + l31) * 128 +
                                              (((2 * s + hi) ^ (lane & 15)) * 8)];
        st[grp] = __builtin_amdgcn_mfma_f32_32x32x16_bf16(ka, qb[s], st[grp], 0, 0, 0);
      }
    __builtin_amdgcn_s_setprio(0);

    // hoist V B-frags (ds_read latency hides under softmax VALU)
    s16x8 vb[4][4];
#pragma unroll
    for (int s = 0; s < 4; ++s)
#pragma unroll
      for (int d = 0; d < 4; ++d)
        vb[s][d] = *(const s16x8*)&Vs[b][(d * 32 + l31) * 64 +
                                         (((2 * s + hi) ^ (lane & 7)) * 8)];

    if (t == NTILES - 1) {  // keys 3120..3135 invalid: grp1 regs 8..15
#pragma unroll
      for (int r = 8; r < 16; ++r) st[1][r] = NEGBIG;  // exp2 -> 0
    }
    // P = exp2(S): fixed scale, lane-local sums, pack bf16, partner exchange
    unsigned W[16], X[16];
    float p0s = 0.f, p1s = 0.f, p2s = 0.f, p3s = 0.f;
#pragma unroll
    for (int grp = 0; grp < 2; ++grp)
#pragma unroll
      for (int i = 0; i < 8; ++i) {
        const float p0 = exp2f(st[grp][2 * i]);
        const float p1 = exp2f(st[grp][2 * i + 1]);
        if (grp) { p2s += p0; p3s += p1; } else { p0s += p0; p1s += p1; }
        W[grp * 8 + i] = cvtpk(p0, p1);
      }
    sl += (p0s + p1s) + (p2s + p3s);
#pragma unroll
    for (int j = 0; j < 16; ++j) X[j] = __shfl_xor((int)W[j], 32);

    // O += P V
    __builtin_amdgcn_s_setprio(1);
#pragma unroll
    for (int s = 0; s < 4; ++s) {
      const int base = (s >> 1) * 8 + (s & 1) * 4;
      unsigned pw[4];
      pw[0] = hi ? X[base + 2] : W[base + 0];
      pw[1] = hi ? X[base + 3] : W[base + 1];
      pw[2] = hi ? W[base + 2] : X[base + 0];
      pw[3] = hi ? W[base + 3] : X[base + 1];
      const s16x8 pa = *(const s16x8*)pw;
#pragma unroll
      for (int d = 0; d < 4; ++d)
        o[d] = __builtin_amdgcn_mfma_f32_32x32x16_bf16(pa, vb[s][d], o[d], 0, 0, 0);
    }
    __builtin_amdgcn_s_setprio(0);
    __builtin_amdgcn_s_barrier();
    __builtin_amdgcn_sched_barrier(0);
  }

  sl += __shfl_xor(sl, 32);
  const float rs = 1.0f / sl;
#pragma unroll
  for (int r = 0; r < 16; ++r) {
    const float rq = __shfl(rs, CROW(r, hi));
    const int row = blockIdx.x * 160 + w * 32 + CROW(r, hi);
    if (row < SEQ) {
#pragma unroll
      for (int d = 0; d < 4; ++d)
        AttO[(size_t)row * DIM + h * HD + d * 32 + l31] = f2bf(o[d][r] * rq);
    }
  }
}

// ---------------------------------------------------------------------------
extern "C" void kernel_launch(void* const* d_in, const int* in_sizes, int n_in,
                              void* d_out, int out_size, void* d_ws, size_t ws_size,
                              hipStream_t stream) {
  const float* x    = (const float*)d_in[0];
  const float* freqs= (const float*)d_in[1];
  const float* Wq   = (const float*)d_in[2];
  const float* bq   = (const float*)d_in[3];
  const float* gq   = (const float*)d_in[4];
  const float* Wk   = (const float*)d_in[5];
  const float* bk   = (const float*)d_in[6];
  const float* gk   = (const float*)d_in[7];
  const float* Wv   = (const float*)d_in[8];
  const float* bv   = (const float*)d_in[9];
  const float* Wo   = (const float*)d_in[10];
  const float* bo   = (const float*)d_in[11];
  const float* qkfb = (const float*)d_in[12];
  const float* vfb  = (const float*)d_in[13];
  const float* vsb  = (const float*)d_in[14];

  if (ws_size < (size_t)87705600) return;

  char* ws = (char*)d_ws;
  u16*   xb    = (u16*)(ws);               // [3200][1536] bf16
  u16*   Vt    = (u16*)(ws);               // alias: xb dead after QKV GEMM
  u16*   WtAll = (u16*)(ws + 9830400);     // [4608][1536] bf16 (Wq|Wk|Wv)^T
  u16*   WoT   = (u16*)(ws + 23986176);    // [1536][1536] bf16 Wo^T
  float* bcat  = (float*)(ws + 28704768);  // [4608]
  u16*   Pqkv  = (u16*)(ws + 28723200);    // [3200][4608] bf16
  u16*   AttO  = (u16*)(ws + 28723200);    // alias: Pqkv dead after k_post
  u16*   Qf    = (u16*)(ws + 58214400);    // [3200][1536] bf16
  u16*   Kf    = (u16*)(ws + 68044800);    // [3200][1536] bf16
  u16*   Vf    = (u16*)(ws + 77875200);    // [3200][1536] bf16

  k_convert_x<<<4800, 256, 0, stream>>>(x, bq, bk, bv, xb, bcat);
  k_transpose_w<<<dim3(48, 48, 4), 256, 0, stream>>>(Wq, Wk, Wv, Wo, WtAll, WoT);
  k_gemm<1><<<900, 256, 0, stream>>>(xb, WtAll, bcat, Pqkv, NQKV, DIM, SPAD, 36);
  k_post<<<SEQ, 256, 0, stream>>>(Pqkv, freqs, gq, gk, qkfb, vfb, vsb, Qf, Kf, Vf);
  k_transpose_v<<<dim3(50, 24), 256, 0, stream>>>(Vf, Vt);
  k_attn<<<dim3(20, 12), 320, 0, stream>>>(Qf, Kf, Vt, AttO);
  k_gemm<0><<<300, 256, 0, stream>>>(AttO, WoT, bo, d_out, DIM, DIM, SEQ, 12);
}

// Round 13
// 255.224 us; speedup vs baseline: 1.3553x; 1.0168x over previous
//
#include <hip/hip_runtime.h>
#include <cstdint>

#define SEQ     3120
#define SPAD    3200
#define DIM     1536
#define NQKV    4608
#define HEADS   12
#define HD      128
#define SPATIAL 390
#define EPSV    1e-5f
#define KVBLK   64
#define NTILES  49
#define NEGBIG  (-1e30f)
// 1/sqrt(128) * log2(e): attention scores computed in log2 domain.
// FIXED-scale softmax (no running max): |s| <= ~12 in log2 domain, so
// exp2(s) <= 4096 and sum <= ~1e7 -- safely inside fp32; softmax is exactly
// scale-invariant, and bf16 relative precision is scale-free.
#define QSCALE  (0.08838834764831845f * 1.4426950408889634f)
#define CROW(r, hi) ((((r) & 3) + 8 * ((r) >> 2)) + 4 * (hi))

typedef unsigned short u16;
typedef short s16x8 __attribute__((ext_vector_type(8)));
typedef float f32x4 __attribute__((ext_vector_type(4)));
typedef float f32x16 __attribute__((ext_vector_type(16)));

__device__ __forceinline__ u16 f2bf(float f) {
  union { float f; unsigned u; } v; v.f = f;
  unsigned r = v.u + 0x7FFFu + ((v.u >> 16) & 1u);
  return (u16)(r >> 16);
}
__device__ __forceinline__ float bf2f(u16 b) {
  union { unsigned u; float f; } v; v.u = ((unsigned)b) << 16;
  return v.f;
}
__device__ __forceinline__ unsigned cvtpk(float lo, float hi) {
  unsigned r;
  asm("v_cvt_pk_bf16_f32 %0, %1, %2" : "=v"(r) : "v"(lo), "v"(hi));
  return r;
}
// async global->LDS, 16B per lane. LDS dest = wave-uniform base + lane*16.
__device__ __forceinline__ void gload16(const void* g, const void* l) {
  __builtin_amdgcn_global_load_lds(
      (const __attribute__((address_space(1))) unsigned*)g,
      (__attribute__((address_space(3))) unsigned*)(uintptr_t)l,
      16, 0, 0);
}

// ------- 1. convert x fp32 -> bf16 (pad [SEQ,SPAD) rows with 0) + biascat --
__global__ __launch_bounds__(256) void k_convert_x(
    const float* __restrict__ x, const float* __restrict__ bq,
    const float* __restrict__ bk, const float* __restrict__ bv,
    u16* __restrict__ xb, float* __restrict__ bcat) {
  if (blockIdx.x == 0) {
    for (int j = threadIdx.x; j < NQKV; j += 256)
      bcat[j] = (j < DIM) ? bq[j] : (j < 2 * DIM) ? bk[j - DIM] : bv[j - 2 * DIM];
  }
  const int i = (blockIdx.x * 256 + threadIdx.x) * 4;
  if (i >= SPAD * DIM) return;
  const int row = i / DIM;
  float4 v = make_float4(0.f, 0.f, 0.f, 0.f);
  if (row < SEQ) v = *(const float4*)(x + i);
  const unsigned lo = (unsigned)f2bf(v.x) | ((unsigned)f2bf(v.y) << 16);
  const unsigned hi = (unsigned)f2bf(v.z) | ((unsigned)f2bf(v.w) << 16);
  *(uint2*)(xb + i) = make_uint2(lo, hi);
}

// ---------------- 2. transpose+convert weights: Wt[n][k] = W[k][n] ---------
// 64x64 tiles; stores packed 2xbf16 (4B/lane, 128B/row-segment).
__global__ __launch_bounds__(256) void k_transpose_w(
    const float* __restrict__ Wq, const float* __restrict__ Wk,
    const float* __restrict__ Wv, const float* __restrict__ Wo,
    u16* __restrict__ WtAll, u16* __restrict__ WoT) {
  const int wsel = blockIdx.z;
  const float* W = (wsel == 0) ? Wq : (wsel == 1) ? Wk : (wsel == 2) ? Wv : Wo;
  __shared__ float t[64][65];
  const int k0 = blockIdx.x * 64, n0 = blockIdx.y * 64;
  const int c = threadIdx.x & 63, r4 = threadIdx.x >> 6;   // r4 in 0..3
#pragma unroll
  for (int rr = 0; rr < 64; rr += 4)
    t[r4 + rr][c] = W[(size_t)(k0 + r4 + rr) * DIM + n0 + c];
  __syncthreads();
  u16* Wt = (wsel < 3) ? (WtAll + (size_t)wsel * DIM * DIM) : WoT;
  const int kp = threadIdx.x & 31;                         // k-pair 0..31
  const int r8 = threadIdx.x >> 5;                         // 0..7
#pragma unroll
  for (int rr = 0; rr < 64; rr += 8) {
    const int n = r8 + rr;
    const unsigned v = (unsigned)f2bf(t[2 * kp][n]) |
                       ((unsigned)f2bf(t[2 * kp + 1][n]) << 16);
    *(unsigned*)&Wt[(size_t)(n0 + n) * DIM + k0 + 2 * kp] = v;
  }
}

// ------- 4/8. bf16 MFMA GEMM, BK=64, swizzled LDS, XCD-swizzled 1D grid ----
template <int OUT_BF16>
__global__ __launch_bounds__(256) void k_gemm(const u16* __restrict__ A,
                                              const u16* __restrict__ Bt,
                                              const float* __restrict__ bias,
                                              void* __restrict__ Cout,
                                              int N, int K, int storeMmax,
                                              int nbx) {
  __shared__ short As[8192];  // [128][64] swizzled
  __shared__ short Bs[8192];
  const int nwg = gridDim.x;
  const int q = nwg >> 3, r = nwg & 7;
  const int xcd = blockIdx.x & 7, idx = blockIdx.x >> 3;
  const int swz = (xcd < r ? xcd * (q + 1) : r * (q + 1) + (xcd - r) * q) + idx;
  const int bxi = swz % nbx, byi = swz / nbx;
  const int brow = byi * 128, bcol = bxi * 128;

  const int tid = threadIdx.x;
  const int lane = tid & 63, wv = tid >> 6;
  const int l15 = lane & 15, g = lane >> 4;
  const int wr = wv >> 1, wc = wv & 1;

  const f32x4 z4 = {0.f, 0.f, 0.f, 0.f};
  f32x4 acc[4][4];
#pragma unroll
  for (int m = 0; m < 4; ++m)
#pragma unroll
    for (int n = 0; n < 4; ++n) acc[m][n] = z4;

  const u16* Ap[4];
  const u16* Bp[4];
  const int sch = ((lane & 7) ^ ((lane >> 3) & 7)) * 8;
#pragma unroll
  for (int it = 0; it < 4; ++it) {
    const int row = it * 32 + wv * 8 + (lane >> 3);
    Ap[it] = A + (size_t)(brow + row) * K + sch;
    Bp[it] = Bt + (size_t)(bcol + row) * K + sch;
  }

  for (int k0 = 0; k0 < K; k0 += 64) {
    __syncthreads();
#pragma unroll
    for (int it = 0; it < 4; ++it) {
      gload16(Ap[it] + k0, As + (it * 32 + wv * 8) * 64);
      gload16(Bp[it] + k0, Bs + (it * 32 + wv * 8) * 64);
    }
    __syncthreads();
#pragma unroll
    for (int kk = 0; kk < 2; ++kk) {
      s16x8 a[4], b[4];
#pragma unroll
      for (int m = 0; m < 4; ++m)
        a[m] = *(const s16x8*)&As[(wr * 64 + m * 16 + l15) * 64 +
                                  (((kk * 4 + g) ^ (l15 & 7)) * 8)];
#pragma unroll
      for (int n = 0; n < 4; ++n)
        b[n] = *(const s16x8*)&Bs[(wc * 64 + n * 16 + l15) * 64 +
                                  (((kk * 4 + g) ^ (l15 & 7)) * 8)];
#pragma unroll
      for (int m = 0; m < 4; ++m)
#pragma unroll
        for (int n = 0; n < 4; ++n)
          acc[m][n] = __builtin_amdgcn_mfma_f32_16x16x32_bf16(a[m], b[n], acc[m][n], 0, 0, 0);
    }
  }

#pragma unroll
  for (int m = 0; m < 4; ++m) {
#pragma unroll
    for (int n = 0; n < 4; ++n) {
      const int cc = bcol + wc * 64 + n * 16 + l15;
      const float bb = bias[cc];
#pragma unroll
      for (int i = 0; i < 4; ++i) {
        const int rr = brow + wr * 64 + m * 16 + g * 4 + i;
        if (rr < storeMmax) {
          const float v = acc[m][n][i] + bb;
          if (OUT_BF16) ((u16*)Cout)[(size_t)rr * N + cc] = f2bf(v);
          else          ((float*)Cout)[(size_t)rr * N + cc] = v;
        }
      }
    }
  }
}

// ---------------- 5. per-token: rmsnorm + rope + biases (vectorized) -------
// 192 active lanes x 8 contiguous channels each; short8/float4/uint4 I/O.
__global__ __launch_bounds__(256) void k_post(
    const u16* __restrict__ Pqkv, const float* __restrict__ freqs,
    const float* __restrict__ gq, const float* __restrict__ gk,
    const float* __restrict__ qkfb, const float* __restrict__ vfb,
    const float* __restrict__ vsb,
    u16* __restrict__ Qf, u16* __restrict__ Kf, u16* __restrict__ Vf) {
  const int s = blockIdx.x;
  const int t = threadIdx.x;
  const int fidx = s / SPATIAL;
  const int sp = s - fidx * SPATIAL;
  __shared__ float cs[64], sn[64];
  __shared__ float red[8];
  if (t < 64) {
    const float a = freqs[s * 64 + t];
    cs[t] = __cosf(a);
    sn[t] = __sinf(a);
  }
  const u16* qrow = Pqkv + (size_t)s * NQKV;
  const u16* krow = qrow + DIM;
  const u16* vrow = qrow + 2 * DIM;
  s16x8 q8, k8, v8;
  float sq = 0.f, sk = 0.f;
  if (t < 192) {
    q8 = *(const s16x8*)(qrow + 8 * t);
    k8 = *(const s16x8*)(krow + 8 * t);
    v8 = *(const s16x8*)(vrow + 8 * t);
#pragma unroll
    for (int i = 0; i < 8; ++i) {
      const float a = bf2f((u16)q8[i]); sq += a * a;
      const float b = bf2f((u16)k8[i]); sk += b * b;
    }
  }
#pragma unroll
  for (int off = 1; off < 64; off <<= 1) {
    sq += __shfl_xor(sq, off);
    sk += __shfl_xor(sk, off);
  }
  const int lane = t & 63, wv = t >> 6;
  if (lane == 0) { red[wv] = sq; red[wv + 4] = sk; }
  __syncthreads();
  sq = red[0] + red[1] + red[2] + red[3];
  sk = red[4] + red[5] + red[6] + red[7];
  const float rq = rsqrtf(sq * (1.0f / DIM) + EPSV);
  const float rk = rsqrtf(sk * (1.0f / DIM) + EPSV);
  if (t >= 192) return;
  const int d0 = 8 * t;
  float GQ[8], GK[8], FB[8], VF[8], VS[8];
  *(float4*)&GQ[0] = *(const float4*)(gq + d0);
  *(float4*)&GQ[4] = *(const float4*)(gq + d0 + 4);
  *(float4*)&GK[0] = *(const float4*)(gk + d0);
  *(float4*)&GK[4] = *(const float4*)(gk + d0 + 4);
  *(float4*)&FB[0] = *(const float4*)(qkfb + fidx * DIM + d0);
  *(float4*)&FB[4] = *(const float4*)(qkfb + fidx * DIM + d0 + 4);
  *(float4*)&VF[0] = *(const float4*)(vfb + fidx * DIM + d0);
  *(float4*)&VF[4] = *(const float4*)(vfb + fidx * DIM + d0 + 4);
  *(float4*)&VS[0] = *(const float4*)(vsb + (size_t)sp * DIM + d0);
  *(float4*)&VS[4] = *(const float4*)(vsb + (size_t)sp * DIM + d0 + 4);
  unsigned qo[4], ko[4], vo[4];
#pragma unroll
  for (int pi = 0; pi < 4; ++pi) {
    const int pin = (4 * t + pi) & 63;
    const float c = cs[pin], s_ = sn[pin];
    float xr = bf2f((u16)q8[2 * pi]) * rq * GQ[2 * pi];
    float xi = bf2f((u16)q8[2 * pi + 1]) * rq * GQ[2 * pi + 1];
    const float q0 = (xr * c - xi * s_ + FB[2 * pi]) * QSCALE;
    const float q1 = (xr * s_ + xi * c + FB[2 * pi + 1]) * QSCALE;
    qo[pi] = (unsigned)f2bf(q0) | ((unsigned)f2bf(q1) << 16);
    xr = bf2f((u16)k8[2 * pi]) * rk * GK[2 * pi];
    xi = bf2f((u16)k8[2 * pi + 1]) * rk * GK[2 * pi + 1];
    const float kk0 = xr * c - xi * s_ + FB[2 * pi];
    const float kk1 = xr * s_ + xi * c + FB[2 * pi + 1];
    ko[pi] = (unsigned)f2bf(kk0) | ((unsigned)f2bf(kk1) << 16);
    const float v0 = bf2f((u16)v8[2 * pi]) + VF[2 * pi] + VS[2 * pi];
    const float v1 = bf2f((u16)v8[2 * pi + 1]) + VF[2 * pi + 1] + VS[2 * pi + 1];
    vo[pi] = (unsigned)f2bf(v0) | ((unsigned)f2bf(v1) << 16);
  }
  *(uint4*)(Qf + (size_t)s * DIM + d0) = make_uint4(qo[0], qo[1], qo[2], qo[3]);
  *(uint4*)(Kf + (size_t)s * DIM + d0) = make_uint4(ko[0], ko[1], ko[2], ko[3]);
  *(uint4*)(Vf + (size_t)s * DIM + d0) = make_uint4(vo[0], vo[1], vo[2], vo[3]);
}

// ---------------- 6. V transpose: Vf[s][1536] -> Vt[dglob][SPAD] -----------
__global__ __launch_bounds__(256) void k_transpose_v(const u16* __restrict__ Vf,
                                                     u16* __restrict__ Vt) {
  __shared__ u16 tile[64][65];
  const int s0 = blockIdx.x * 64, c0 = blockIdx.y * 64;
  const int c = threadIdx.x & 63, r4 = threadIdx.x >> 6;
#pragma unroll
  for (int rr = 0; rr < 64; rr += 4) {
    const int s = s0 + r4 + rr;
    tile[r4 + rr][c] = (s < SEQ) ? Vf[(size_t)s * DIM + c0 + c] : (u16)0;
  }
  __syncthreads();
#pragma unroll
  for (int rr = 0; rr < 64; rr += 4) {
    const int dglob = c0 + r4 + rr;
    Vt[(size_t)dglob * SPAD + s0 + c] = tile[c][r4 + rr];
  }
}

// ---------------- 7. flash attention (R8 kernel + head->XCD grouping) ------
// 1D grid 240: gb = (bid&7)*30 + (bid>>3); h = gb/20, bx = gb%20. Assuming
// round-robin bid->XCD dispatch, each head's 20 blocks land on <=2 XCDs so
// that head's K/V (1.6MB) stays L2-resident. Perf heuristic only (G16-safe).
// 320 threads = 5 warps, 128 VGPR, no spill; FIXED-scale softmax.
__global__ __launch_bounds__(320, 2) void k_attn(const u16* __restrict__ Qf,
                                                 const u16* __restrict__ Kf,
                                                 const u16* __restrict__ Vt,
                                                 u16* __restrict__ AttO) {
  __shared__ short Ks[2][8192];  // [64 key][16 chunk][8]
  __shared__ short Vs[2][8192];  // [128 d][8 chunk][8]
  const int bid = blockIdx.x;
  const int gb = (bid & 7) * 30 + (bid >> 3);
  const int h = gb / 20;
  const int bx = gb - h * 20;
  const int tid = threadIdx.x;
  const int lane = tid & 63, w = tid >> 6;     // w in 0..4
  const int l31 = lane & 31, hi = lane >> 5;
  const int qrow = bx * 160 + w * 32 + l31;

  // Q B-frags: qb[s] = Q[qrow][16s + 8hi + j]
  s16x8 qb[8];
  {
    const u16* qp = Qf + (size_t)qrow * DIM + h * HD + hi * 8;
#pragma unroll
    for (int s = 0; s < 8; ++s) qb[s] = *(const s16x8*)(qp + s * 16);
  }

  f32x16 o[4];
#pragma unroll
  for (int d = 0; d < 4; ++d)
#pragma unroll
    for (int r = 0; r < 16; ++r) o[d][r] = 0.f;
  float sl = 0.f;

  // staging pointers (warps 0..3 only)
  const u16* Kp[4];
  const u16* Vp[4];
  if (w < 4) {
#pragma unroll
    for (int it = 0; it < 4; ++it) {
      const int krow = w * 16 + it * 4 + (lane >> 4);
      const int kch = (lane & 15) ^ (it * 4 + (lane >> 4));
      Kp[it] = Kf + (size_t)krow * DIM + h * HD + kch * 8;
      const int vrow = w * 32 + it * 8 + (lane >> 3);
      const int vch = (lane & 7) ^ (lane >> 3);
      Vp[it] = Vt + (size_t)(h * HD + vrow) * SPAD + vch * 8;
    }
  }
  auto stage = [&](int T, int B) {
    const size_t kof = (size_t)T * KVBLK * DIM;
    const int vof = T * KVBLK;
#pragma unroll
    for (int it = 0; it < 4; ++it) {
      gload16(Kp[it] + kof, &Ks[B][(w * 16 + it * 4) * 128]);
      gload16(Vp[it] + vof, &Vs[B][(w * 32 + it * 8) * 64]);
    }
  };

  if (w < 4) {
    asm volatile("s_waitcnt vmcnt(0)" ::: "memory");
    stage(0, 0);
  }

  for (int t = 0; t < NTILES; ++t) {
    const int b = t & 1;
    if (w < 4) {
      if (t + 1 < NTILES) {
        stage(t + 1, b ^ 1);
        asm volatile("s_waitcnt vmcnt(8)" ::: "memory");
      } else {
        asm volatile("s_waitcnt vmcnt(0)" ::: "memory");
      }
    }
    __builtin_amdgcn_s_barrier();
    __builtin_amdgcn_sched_barrier(0);

    // S^T = K Q  (D[key][q]: col q = l31, row key = CROW(r,hi) per grp of 32)
    f32x16 st[2];
#pragma unroll
    for (int r = 0; r < 16; ++r) { st[0][r] = 0.f; st[1][r] = 0.f; }
    __builtin_amdgcn_s_setprio(1);
#pragma unroll
    for (int grp = 0; grp < 2; ++grp)
#pragma unroll
      for (int s = 0; s < 8; ++s) {
        const s16x8 ka = *(const s16x8*)&Ks[b][(grp * 32 + l31) * 128 +
                                              (((2 * s + hi) ^ (lane & 15)) * 8)];
        st[grp] = __builtin_amdgcn_mfma_f32_32x32x16_bf16(ka, qb[s], st[grp], 0, 0, 0);
      }
    __builtin_amdgcn_s_setprio(0);

    // hoist V B-frags (ds_read latency hides under softmax VALU)
    s16x8 vb[4][4];
#pragma unroll
    for (int s = 0; s < 4; ++s)
#pragma unroll
      for (int d = 0; d < 4; ++d)
        vb[s][d] = *(const s16x8*)&Vs[b][(d * 32 + l31) * 64 +
                                         (((2 * s + hi) ^ (lane & 7)) * 8)];

    if (t == NTILES - 1) {  // keys 3120..3135 invalid: grp1 regs 8..15
#pragma unroll
      for (int r = 8; r < 16; ++r) st[1][r] = NEGBIG;  // exp2 -> 0
    }
    // P = exp2(S): fixed scale, lane-local sums, pack bf16, partner exchange
    unsigned W[16], X[16];
    float p0s = 0.f, p1s = 0.f, p2s = 0.f, p3s = 0.f;
#pragma unroll
    for (int grp = 0; grp < 2; ++grp)
#pragma unroll
      for (int i = 0; i < 8; ++i) {
        const float p0 = exp2f(st[grp][2 * i]);
        const float p1 = exp2f(st[grp][2 * i + 1]);
        if (grp) { p2s += p0; p3s += p1; } else { p0s += p0; p1s += p1; }
        W[grp * 8 + i] = cvtpk(p0, p1);
      }
    sl += (p0s + p1s) + (p2s + p3s);
#pragma unroll
    for (int j = 0; j < 16; ++j) X[j] = __shfl_xor((int)W[j], 32);

    // O += P V
    __builtin_amdgcn_s_setprio(1);
#pragma unroll
    for (int s = 0; s < 4; ++s) {
      const int base = (s >> 1) * 8 + (s & 1) * 4;
      unsigned pw[4];
      pw[0] = hi ? X[base + 2] : W[base + 0];
      pw[1] = hi ? X[base + 3] : W[base + 1];
      pw[2] = hi ? W[base + 2] : X[base + 0];
      pw[3] = hi ? W[base + 3] : X[base + 1];
      const s16x8 pa = *(const s16x8*)pw;
#pragma unroll
      for (int d = 0; d < 4; ++d)
        o[d] = __builtin_amdgcn_mfma_f32_32x32x16_bf16(pa, vb[s][d], o[d], 0, 0, 0);
    }
    __builtin_amdgcn_s_setprio(0);
    __builtin_amdgcn_s_barrier();
    __builtin_amdgcn_sched_barrier(0);
  }

  sl += __shfl_xor(sl, 32);
  const float rs = 1.0f / sl;
#pragma unroll
  for (int r = 0; r < 16; ++r) {
    const float rq = __shfl(rs, CROW(r, hi));
    const int row = bx * 160 + w * 32 + CROW(r, hi);
    if (row < SEQ) {
#pragma unroll
      for (int d = 0; d < 4; ++d)
        AttO[(size_t)row * DIM + h * HD + d * 32 + l31] = f2bf(o[d][r] * rq);
    }
  }
}

// ---------------------------------------------------------------------------
extern "C" void kernel_launch(void* const* d_in, const int* in_sizes, int n_in,
                              void* d_out, int out_size, void* d_ws, size_t ws_size,
                              hipStream_t stream) {
  const float* x    = (const float*)d_in[0];
  const float* freqs= (const float*)d_in[1];
  const float* Wq   = (const float*)d_in[2];
  const float* bq   = (const float*)d_in[3];
  const float* gq   = (const float*)d_in[4];
  const float* Wk   = (const float*)d_in[5];
  const float* bk   = (const float*)d_in[6];
  const float* gk   = (const float*)d_in[7];
  const float* Wv   = (const float*)d_in[8];
  const float* bv   = (const float*)d_in[9];
  const float* Wo   = (const float*)d_in[10];
  const float* bo   = (const float*)d_in[11];
  const float* qkfb = (const float*)d_in[12];
  const float* vfb  = (const float*)d_in[13];
  const float* vsb  = (const float*)d_in[14];

  if (ws_size < (size_t)87705600) return;

  char* ws = (char*)d_ws;
  u16*   xb    = (u16*)(ws);               // [3200][1536] bf16
  u16*   Vt    = (u16*)(ws);               // alias: xb dead after QKV GEMM
  u16*   WtAll = (u16*)(ws + 9830400);     // [4608][1536] bf16 (Wq|Wk|Wv)^T
  u16*   WoT   = (u16*)(ws + 23986176);    // [1536][1536] bf16 Wo^T
  float* bcat  = (float*)(ws + 28704768);  // [4608]
  u16*   Pqkv  = (u16*)(ws + 28723200);    // [3200][4608] bf16
  u16*   AttO  = (u16*)(ws + 28723200);    // alias: Pqkv dead after k_post
  u16*   Qf    = (u16*)(ws + 58214400);    // [3200][1536] bf16
  u16*   Kf    = (u16*)(ws + 68044800);    // [3200][1536] bf16
  u16*   Vf    = (u16*)(ws + 77875200);    // [3200][1536] bf16

  k_convert_x<<<4800, 256, 0, stream>>>(x, bq, bk, bv, xb, bcat);
  k_transpose_w<<<dim3(24, 24, 4), 256, 0, stream>>>(Wq, Wk, Wv, Wo, WtAll, WoT);
  k_gemm<1><<<900, 256, 0, stream>>>(xb, WtAll, bcat, Pqkv, NQKV, DIM, SPAD, 36);
  k_post<<<SEQ, 256, 0, stream>>>(Pqkv, freqs, gq, gk, qkfb, vfb, vsb, Qf, Kf, Vf);
  k_transpose_v<<<dim3(50, 24), 256, 0, stream>>>(Vf, Vt);
  k_attn<<<240, 320, 0, stream>>>(Qf, Kf, Vt, AttO);
  k_gemm<0><<<300, 256, 0, stream>>>(AttO, WoT, bo, d_out, DIM, DIM, SEQ, 12);
}

// Round 14
// 245.608 us; speedup vs baseline: 1.4084x; 1.0392x over previous
//
#include <hip/hip_runtime.h>
#include <cstdint>

#define SEQ     3120
#define SPAD    3200
#define DIM     1536
#define NQKV    4608
#define HEADS   12
#define HD      128
#define SPATIAL 390
#define EPSV    1e-5f
#define KVBLK   64
#define NTILES  49
#define NEGBIG  (-1e30f)
// 1/sqrt(128) * log2(e): attention scores computed in log2 domain.
// FIXED-scale softmax (no running max): |s| <= ~12 in log2 domain, so
// exp2(s) <= 4096 and sum <= ~1e7 -- safely inside fp32; softmax is exactly
// scale-invariant, and bf16 relative precision is scale-free.
#define QSCALE  (0.08838834764831845f * 1.4426950408889634f)
#define CROW(r, hi) ((((r) & 3) + 8 * ((r) >> 2)) + 4 * (hi))

typedef unsigned short u16;
typedef short s16x8 __attribute__((ext_vector_type(8)));
typedef float f32x4 __attribute__((ext_vector_type(4)));
typedef float f32x16 __attribute__((ext_vector_type(16)));

__device__ __forceinline__ u16 f2bf(float f) {
  union { float f; unsigned u; } v; v.f = f;
  unsigned r = v.u + 0x7FFFu + ((v.u >> 16) & 1u);
  return (u16)(r >> 16);
}
__device__ __forceinline__ float bf2f(u16 b) {
  union { unsigned u; float f; } v; v.u = ((unsigned)b) << 16;
  return v.f;
}
__device__ __forceinline__ unsigned cvtpk(float lo, float hi) {
  unsigned r;
  asm("v_cvt_pk_bf16_f32 %0, %1, %2" : "=v"(r) : "v"(lo), "v"(hi));
  return r;
}
// async global->LDS, 16B per lane. LDS dest = wave-uniform base + lane*16.
__device__ __forceinline__ void gload16(const void* g, const void* l) {
  __builtin_amdgcn_global_load_lds(
      (const __attribute__((address_space(1))) unsigned*)g,
      (__attribute__((address_space(3))) unsigned*)(uintptr_t)l,
      16, 0, 0);
}

// ------- 1+2 fused prep: blocks [0,4800) convert x + biascat; -------------
//         blocks [4800,7104) transpose+convert the 4 weight matrices.
__global__ __launch_bounds__(256) void k_prep(
    const float* __restrict__ x, const float* __restrict__ bq,
    const float* __restrict__ bk, const float* __restrict__ bv,
    const float* __restrict__ Wq, const float* __restrict__ Wk,
    const float* __restrict__ Wv, const float* __restrict__ Wo,
    u16* __restrict__ xb, float* __restrict__ bcat,
    u16* __restrict__ WtAll, u16* __restrict__ WoT) {
  __shared__ float t[64][65];
  const int bid = blockIdx.x;
  if (bid < 4800) {
    // ---- convert x fp32 -> bf16, pad rows [SEQ,SPAD) with 0; biascat -----
    if (bid == 0) {
      for (int j = threadIdx.x; j < NQKV; j += 256)
        bcat[j] = (j < DIM) ? bq[j] : (j < 2 * DIM) ? bk[j - DIM] : bv[j - 2 * DIM];
    }
    const int i = (bid * 256 + threadIdx.x) * 4;
    if (i >= SPAD * DIM) return;
    const int row = i / DIM;
    float4 v = make_float4(0.f, 0.f, 0.f, 0.f);
    if (row < SEQ) v = *(const float4*)(x + i);
    const unsigned lo = (unsigned)f2bf(v.x) | ((unsigned)f2bf(v.y) << 16);
    const unsigned hi = (unsigned)f2bf(v.z) | ((unsigned)f2bf(v.w) << 16);
    *(uint2*)(xb + i) = make_uint2(lo, hi);
  } else {
    // ---- transpose weights: Wt[n][k] = W[k][n], 64x64 tiles --------------
    const int tb = bid - 4800;              // 0..2303
    const int wsel = tb / 576;              // 576 = 24*24
    const int rem = tb - wsel * 576;
    const int byi = rem / 24, bxi = rem - (rem / 24) * 24;
    const float* W = (wsel == 0) ? Wq : (wsel == 1) ? Wk : (wsel == 2) ? Wv : Wo;
    const int k0 = bxi * 64, n0 = byi * 64;
    const int c = threadIdx.x & 63, r4 = threadIdx.x >> 6;
#pragma unroll
    for (int rr = 0; rr < 64; rr += 4)
      t[r4 + rr][c] = W[(size_t)(k0 + r4 + rr) * DIM + n0 + c];
    __syncthreads();
    u16* Wt = (wsel < 3) ? (WtAll + (size_t)wsel * DIM * DIM) : WoT;
    const int kp = threadIdx.x & 31;
    const int r8 = threadIdx.x >> 5;
#pragma unroll
    for (int rr = 0; rr < 64; rr += 8) {
      const int n = r8 + rr;
      const unsigned v = (unsigned)f2bf(t[2 * kp][n]) |
                         ((unsigned)f2bf(t[2 * kp + 1][n]) << 16);
      *(unsigned*)&Wt[(size_t)(n0 + n) * DIM + k0 + 2 * kp] = v;
    }
  }
}

// ------- 4/8. bf16 MFMA GEMM, BK=64, dbuf + counted vmcnt (attn pattern) --
// stage(t+1) -> vmcnt(8) -> barrier -> compute(t) -> barrier: tile t+1's
// loads stay in flight across the barriers instead of a full drain per step.
// LDS 2x(16KB A + 16KB B) = 64KB -> 2 blocks/CU. Same summation order.
template <int OUT_BF16>
__global__ __launch_bounds__(256) void k_gemm(const u16* __restrict__ A,
                                              const u16* __restrict__ Bt,
                                              const float* __restrict__ bias,
                                              void* __restrict__ Cout,
                                              int N, int K, int storeMmax,
                                              int nbx) {
  __shared__ short As[2][8192];  // [128][64] swizzled
  __shared__ short Bs[2][8192];
  const int nwg = gridDim.x;
  const int q = nwg >> 3, r = nwg & 7;
  const int xcd = blockIdx.x & 7, idx = blockIdx.x >> 3;
  const int swz = (xcd < r ? xcd * (q + 1) : r * (q + 1) + (xcd - r) * q) + idx;
  const int bxi = swz % nbx, byi = swz / nbx;
  const int brow = byi * 128, bcol = bxi * 128;

  const int tid = threadIdx.x;
  const int lane = tid & 63, wv = tid >> 6;
  const int l15 = lane & 15, g = lane >> 4;
  const int wr = wv >> 1, wc = wv & 1;

  const f32x4 z4 = {0.f, 0.f, 0.f, 0.f};
  f32x4 acc[4][4];
#pragma unroll
  for (int m = 0; m < 4; ++m)
#pragma unroll
    for (int n = 0; n < 4; ++n) acc[m][n] = z4;

  const u16* Ap[4];
  const u16* Bp[4];
  const int sch = ((lane & 7) ^ ((lane >> 3) & 7)) * 8;
#pragma unroll
  for (int it = 0; it < 4; ++it) {
    const int row = it * 32 + wv * 8 + (lane >> 3);
    Ap[it] = A + (size_t)(brow + row) * K + sch;
    Bp[it] = Bt + (size_t)(bcol + row) * K + sch;
  }
  auto stage = [&](int T, int B) {
    const int k0 = T * 64;
#pragma unroll
    for (int it = 0; it < 4; ++it) {
      gload16(Ap[it] + k0, &As[B][(it * 32 + wv * 8) * 64]);
      gload16(Bp[it] + k0, &Bs[B][(it * 32 + wv * 8) * 64]);
    }
  };

  const int NK = K >> 6;
  stage(0, 0);

  for (int t = 0; t < NK; ++t) {
    const int b = t & 1;
    if (t + 1 < NK) {
      stage(t + 1, b ^ 1);
      asm volatile("s_waitcnt vmcnt(8)" ::: "memory");  // tile t's 8 done
    } else {
      asm volatile("s_waitcnt vmcnt(0)" ::: "memory");
    }
    __builtin_amdgcn_s_barrier();
    __builtin_amdgcn_sched_barrier(0);
#pragma unroll
    for (int kk = 0; kk < 2; ++kk) {
      s16x8 a[4], bfr[4];
#pragma unroll
      for (int m = 0; m < 4; ++m)
        a[m] = *(const s16x8*)&As[b][(wr * 64 + m * 16 + l15) * 64 +
                                     (((kk * 4 + g) ^ (l15 & 7)) * 8)];
#pragma unroll
      for (int n = 0; n < 4; ++n)
        bfr[n] = *(const s16x8*)&Bs[b][(wc * 64 + n * 16 + l15) * 64 +
                                       (((kk * 4 + g) ^ (l15 & 7)) * 8)];
#pragma unroll
      for (int m = 0; m < 4; ++m)
#pragma unroll
        for (int n = 0; n < 4; ++n)
          acc[m][n] = __builtin_amdgcn_mfma_f32_16x16x32_bf16(a[m], bfr[n], acc[m][n], 0, 0, 0);
    }
    __builtin_amdgcn_s_barrier();  // protect buf b before stage(t+2) writes it
    __builtin_amdgcn_sched_barrier(0);
  }

#pragma unroll
  for (int m = 0; m < 4; ++m) {
#pragma unroll
    for (int n = 0; n < 4; ++n) {
      const int cc = bcol + wc * 64 + n * 16 + l15;
      const float bb = bias[cc];
#pragma unroll
      for (int i = 0; i < 4; ++i) {
        const int rr = brow + wr * 64 + m * 16 + g * 4 + i;
        if (rr < storeMmax) {
          const float v = acc[m][n][i] + bb;
          if (OUT_BF16) ((u16*)Cout)[(size_t)rr * N + cc] = f2bf(v);
          else          ((float*)Cout)[(size_t)rr * N + cc] = v;
        }
      }
    }
  }
}

// ---------------- 5. per-token: rmsnorm + rope + biases (vectorized) -------
__global__ __launch_bounds__(256) void k_post(
    const u16* __restrict__ Pqkv, const float* __restrict__ freqs,
    const float* __restrict__ gq, const float* __restrict__ gk,
    const float* __restrict__ qkfb, const float* __restrict__ vfb,
    const float* __restrict__ vsb,
    u16* __restrict__ Qf, u16* __restrict__ Kf, u16* __restrict__ Vf) {
  const int s = blockIdx.x;
  const int t = threadIdx.x;
  const int fidx = s / SPATIAL;
  const int sp = s - fidx * SPATIAL;
  __shared__ float cs[64], sn[64];
  __shared__ float red[8];
  if (t < 64) {
    const float a = freqs[s * 64 + t];
    cs[t] = __cosf(a);
    sn[t] = __sinf(a);
  }
  const u16* qrow = Pqkv + (size_t)s * NQKV;
  const u16* krow = qrow + DIM;
  const u16* vrow = qrow + 2 * DIM;
  s16x8 q8, k8, v8;
  float sq = 0.f, sk = 0.f;
  if (t < 192) {
    q8 = *(const s16x8*)(qrow + 8 * t);
    k8 = *(const s16x8*)(krow + 8 * t);
    v8 = *(const s16x8*)(vrow + 8 * t);
#pragma unroll
    for (int i = 0; i < 8; ++i) {
      const float a = bf2f((u16)q8[i]); sq += a * a;
      const float b = bf2f((u16)k8[i]); sk += b * b;
    }
  }
#pragma unroll
  for (int off = 1; off < 64; off <<= 1) {
    sq += __shfl_xor(sq, off);
    sk += __shfl_xor(sk, off);
  }
  const int lane = t & 63, wv = t >> 6;
  if (lane == 0) { red[wv] = sq; red[wv + 4] = sk; }
  __syncthreads();
  sq = red[0] + red[1] + red[2] + red[3];
  sk = red[4] + red[5] + red[6] + red[7];
  const float rq = rsqrtf(sq * (1.0f / DIM) + EPSV);
  const float rk = rsqrtf(sk * (1.0f / DIM) + EPSV);
  if (t >= 192) return;
  const int d0 = 8 * t;
  float GQ[8], GK[8], FB[8], VF[8], VS[8];
  *(float4*)&GQ[0] = *(const float4*)(gq + d0);
  *(float4*)&GQ[4] = *(const float4*)(gq + d0 + 4);
  *(float4*)&GK[0] = *(const float4*)(gk + d0);
  *(float4*)&GK[4] = *(const float4*)(gk + d0 + 4);
  *(float4*)&FB[0] = *(const float4*)(qkfb + fidx * DIM + d0);
  *(float4*)&FB[4] = *(const float4*)(qkfb + fidx * DIM + d0 + 4);
  *(float4*)&VF[0] = *(const float4*)(vfb + fidx * DIM + d0);
  *(float4*)&VF[4] = *(const float4*)(vfb + fidx * DIM + d0 + 4);
  *(float4*)&VS[0] = *(const float4*)(vsb + (size_t)sp * DIM + d0);
  *(float4*)&VS[4] = *(const float4*)(vsb + (size_t)sp * DIM + d0 + 4);
  unsigned qo[4], ko[4], vo[4];
#pragma unroll
  for (int pi = 0; pi < 4; ++pi) {
    const int pin = (4 * t + pi) & 63;
    const float c = cs[pin], s_ = sn[pin];
    float xr = bf2f((u16)q8[2 * pi]) * rq * GQ[2 * pi];
    float xi = bf2f((u16)q8[2 * pi + 1]) * rq * GQ[2 * pi + 1];
    const float q0 = (xr * c - xi * s_ + FB[2 * pi]) * QSCALE;
    const float q1 = (xr * s_ + xi * c + FB[2 * pi + 1]) * QSCALE;
    qo[pi] = (unsigned)f2bf(q0) | ((unsigned)f2bf(q1) << 16);
    xr = bf2f((u16)k8[2 * pi]) * rk * GK[2 * pi];
    xi = bf2f((u16)k8[2 * pi + 1]) * rk * GK[2 * pi + 1];
    const float kk0 = xr * c - xi * s_ + FB[2 * pi];
    const float kk1 = xr * s_ + xi * c + FB[2 * pi + 1];
    ko[pi] = (unsigned)f2bf(kk0) | ((unsigned)f2bf(kk1) << 16);
    const float v0 = bf2f((u16)v8[2 * pi]) + VF[2 * pi] + VS[2 * pi];
    const float v1 = bf2f((u16)v8[2 * pi + 1]) + VF[2 * pi + 1] + VS[2 * pi + 1];
    vo[pi] = (unsigned)f2bf(v0) | ((unsigned)f2bf(v1) << 16);
  }
  *(uint4*)(Qf + (size_t)s * DIM + d0) = make_uint4(qo[0], qo[1], qo[2], qo[3]);
  *(uint4*)(Kf + (size_t)s * DIM + d0) = make_uint4(ko[0], ko[1], ko[2], ko[3]);
  *(uint4*)(Vf + (size_t)s * DIM + d0) = make_uint4(vo[0], vo[1], vo[2], vo[3]);
}

// ---------------- 6. V transpose: Vf[s][1536] -> Vt[dglob][SPAD] -----------
__global__ __launch_bounds__(256) void k_transpose_v(const u16* __restrict__ Vf,
                                                     u16* __restrict__ Vt) {
  __shared__ u16 tile[64][65];
  const int s0 = blockIdx.x * 64, c0 = blockIdx.y * 64;
  const int c = threadIdx.x & 63, r4 = threadIdx.x >> 6;
#pragma unroll
  for (int rr = 0; rr < 64; rr += 4) {
    const int s = s0 + r4 + rr;
    tile[r4 + rr][c] = (s < SEQ) ? Vf[(size_t)s * DIM + c0 + c] : (u16)0;
  }
  __syncthreads();
#pragma unroll
  for (int rr = 0; rr < 64; rr += 4) {
    const int dglob = c0 + r4 + rr;
    Vt[(size_t)dglob * SPAD + s0 + c] = tile[c][r4 + rr];
  }
}

// ---------------- 7. flash attention (R8 kernel + head->XCD grouping) ------
// 1D grid 240: gb = (bid&7)*30 + (bid>>3); h = gb/20, bx = gb%20. Each head's
// 20 blocks land on <=2 XCDs so its K/V stays L2-resident (R13: FETCH 80->18MB).
// 320 threads = 5 warps, 128 VGPR, no spill; FIXED-scale softmax.
__global__ __launch_bounds__(320, 2) void k_attn(const u16* __restrict__ Qf,
                                                 const u16* __restrict__ Kf,
                                                 const u16* __restrict__ Vt,
                                                 u16* __restrict__ AttO) {
  __shared__ short Ks[2][8192];  // [64 key][16 chunk][8]
  __shared__ short Vs[2][8192];  // [128 d][8 chunk][8]
  const int bid = blockIdx.x;
  const int gb = (bid & 7) * 30 + (bid >> 3);
  const int h = gb / 20;
  const int bx = gb - h * 20;
  const int tid = threadIdx.x;
  const int lane = tid & 63, w = tid >> 6;     // w in 0..4
  const int l31 = lane & 31, hi = lane >> 5;
  const int qrow = bx * 160 + w * 32 + l31;

  // Q B-frags: qb[s] = Q[qrow][16s + 8hi + j]
  s16x8 qb[8];
  {
    const u16* qp = Qf + (size_t)qrow * DIM + h * HD + hi * 8;
#pragma unroll
    for (int s = 0; s < 8; ++s) qb[s] = *(const s16x8*)(qp + s * 16);
  }

  f32x16 o[4];
#pragma unroll
  for (int d = 0; d < 4; ++d)
#pragma unroll
    for (int r = 0; r < 16; ++r) o[d][r] = 0.f;
  float sl = 0.f;

  // staging pointers (warps 0..3 only)
  const u16* Kp[4];
  const u16* Vp[4];
  if (w < 4) {
#pragma unroll
    for (int it = 0; it < 4; ++it) {
      const int krow = w * 16 + it * 4 + (lane >> 4);
      const int kch = (lane & 15) ^ (it * 4 + (lane >> 4));
      Kp[it] = Kf + (size_t)krow * DIM + h * HD + kch * 8;
      const int vrow = w * 32 + it * 8 + (lane >> 3);
      const int vch = (lane & 7) ^ (lane >> 3);
      Vp[it] = Vt + (size_t)(h * HD + vrow) * SPAD + vch * 8;
    }
  }
  auto stage = [&](int T, int B) {
    const size_t kof = (size_t)T * KVBLK * DIM;
    const int vof = T * KVBLK;
#pragma unroll
    for (int it = 0; it < 4; ++it) {
      gload16(Kp[it] + kof, &Ks[B][(w * 16 + it * 4) * 128]);
      gload16(Vp[it] + vof, &Vs[B][(w * 32 + it * 8) * 64]);
    }
  };

  if (w < 4) {
    asm volatile("s_waitcnt vmcnt(0)" ::: "memory");
    stage(0, 0);
  }

  for (int t = 0; t < NTILES; ++t) {
    const int b = t & 1;
    if (w < 4) {
      if (t + 1 < NTILES) {
        stage(t + 1, b ^ 1);
        asm volatile("s_waitcnt vmcnt(8)" ::: "memory");
      } else {
        asm volatile("s_waitcnt vmcnt(0)" ::: "memory");
      }
    }
    __builtin_amdgcn_s_barrier();
    __builtin_amdgcn_sched_barrier(0);

    // S^T = K Q  (D[key][q]: col q = l31, row key = CROW(r,hi) per grp of 32)
    f32x16 st[2];
#pragma unroll
    for (int r = 0; r < 16; ++r) { st[0][r] = 0.f; st[1][r] = 0.f; }
    __builtin_amdgcn_s_setprio(1);
#pragma unroll
    for (int grp = 0; grp < 2; ++grp)
#pragma unroll
      for (int s = 0; s < 8; ++s) {
        const s16x8 ka = *(const s16x8*)&Ks[b][(grp * 32 + l31) * 128 +
                                              (((2 * s + hi) ^ (lane & 15)) * 8)];
        st[grp] = __builtin_amdgcn_mfma_f32_32x32x16_bf16(ka, qb[s], st[grp], 0, 0, 0);
      }
    __builtin_amdgcn_s_setprio(0);

    // hoist V B-frags (ds_read latency hides under softmax VALU)
    s16x8 vb[4][4];
#pragma unroll
    for (int s = 0; s < 4; ++s)
#pragma unroll
      for (int d = 0; d < 4; ++d)
        vb[s][d] = *(const s16x8*)&Vs[b][(d * 32 + l31) * 64 +
                                         (((2 * s + hi) ^ (lane & 7)) * 8)];

    if (t == NTILES - 1) {  // keys 3120..3135 invalid: grp1 regs 8..15
#pragma unroll
      for (int r = 8; r < 16; ++r) st[1][r] = NEGBIG;  // exp2 -> 0
    }
    // P = exp2(S): fixed scale, lane-local sums, pack bf16, partner exchange
    unsigned W[16], X[16];
    float p0s = 0.f, p1s = 0.f, p2s = 0.f, p3s = 0.f;
#pragma unroll
    for (int grp = 0; grp < 2; ++grp)
#pragma unroll
      for (int i = 0; i < 8; ++i) {
        const float p0 = exp2f(st[grp][2 * i]);
        const float p1 = exp2f(st[grp][2 * i + 1]);
        if (grp) { p2s += p0; p3s += p1; } else { p0s += p0; p1s += p1; }
        W[grp * 8 + i] = cvtpk(p0, p1);
      }
    sl += (p0s + p1s) + (p2s + p3s);
#pragma unroll
    for (int j = 0; j < 16; ++j) X[j] = __shfl_xor((int)W[j], 32);

    // O += P V
    __builtin_amdgcn_s_setprio(1);
#pragma unroll
    for (int s = 0; s < 4; ++s) {
      const int base = (s >> 1) * 8 + (s & 1) * 4;
      unsigned pw[4];
      pw[0] = hi ? X[base + 2] : W[base + 0];
      pw[1] = hi ? X[base + 3] : W[base + 1];
      pw[2] = hi ? W[base + 2] : X[base + 0];
      pw[3] = hi ? W[base + 3] : X[base + 1];
      const s16x8 pa = *(const s16x8*)pw;
#pragma unroll
      for (int d = 0; d < 4; ++d)
        o[d] = __builtin_amdgcn_mfma_f32_32x32x16_bf16(pa, vb[s][d], o[d], 0, 0, 0);
    }
    __builtin_amdgcn_s_setprio(0);
    __builtin_amdgcn_s_barrier();
    __builtin_amdgcn_sched_barrier(0);
  }

  sl += __shfl_xor(sl, 32);
  const float rs = 1.0f / sl;
#pragma unroll
  for (int r = 0; r < 16; ++r) {
    const float rq = __shfl(rs, CROW(r, hi));
    const int row = bx * 160 + w * 32 + CROW(r, hi);
    if (row < SEQ) {
#pragma unroll
      for (int d = 0; d < 4; ++d)
        AttO[(size_t)row * DIM + h * HD + d * 32 + l31] = f2bf(o[d][r] * rq);
    }
  }
}

// ---------------------------------------------------------------------------
extern "C" void kernel_launch(void* const* d_in, const int* in_sizes, int n_in,
                              void* d_out, int out_size, void* d_ws, size_t ws_size,
                              hipStream_t stream) {
  const float* x    = (const float*)d_in[0];
  const float* freqs= (const float*)d_in[1];
  const float* Wq   = (const float*)d_in[2];
  const float* bq   = (const float*)d_in[3];
  const float* gq   = (const float*)d_in[4];
  const float* Wk   = (const float*)d_in[5];
  const float* bk   = (const float*)d_in[6];
  const float* gk   = (const float*)d_in[7];
  const float* Wv   = (const float*)d_in[8];
  const float* bv   = (const float*)d_in[9];
  const float* Wo   = (const float*)d_in[10];
  const float* bo   = (const float*)d_in[11];
  const float* qkfb = (const float*)d_in[12];
  const float* vfb  = (const float*)d_in[13];
  const float* vsb  = (const float*)d_in[14];

  if (ws_size < (size_t)87705600) return;

  char* ws = (char*)d_ws;
  u16*   xb    = (u16*)(ws);               // [3200][1536] bf16
  u16*   Vt    = (u16*)(ws);               // alias: xb dead after QKV GEMM
  u16*   WtAll = (u16*)(ws + 9830400);     // [4608][1536] bf16 (Wq|Wk|Wv)^T
  u16*   WoT   = (u16*)(ws + 23986176);    // [1536][1536] bf16 Wo^T
  float* bcat  = (float*)(ws + 28704768);  // [4608]
  u16*   Pqkv  = (u16*)(ws + 28723200);    // [3200][4608] bf16
  u16*   AttO  = (u16*)(ws + 28723200);    // alias: Pqkv dead after k_post
  u16*   Qf    = (u16*)(ws + 58214400);    // [3200][1536] bf16
  u16*   Kf    = (u16*)(ws + 68044800);    // [3200][1536] bf16
  u16*   Vf    = (u16*)(ws + 77875200);    // [3200][1536] bf16

  k_prep<<<7104, 256, 0, stream>>>(x, bq, bk, bv, Wq, Wk, Wv, Wo,
                                   xb, bcat, WtAll, WoT);
  k_gemm<1><<<900, 256, 0, stream>>>(xb, WtAll, bcat, Pqkv, NQKV, DIM, SPAD, 36);
  k_post<<<SEQ, 256, 0, stream>>>(Pqkv, freqs, gq, gk, qkfb, vfb, vsb, Qf, Kf, Vf);
  k_transpose_v<<<dim3(50, 24), 256, 0, stream>>>(Vf, Vt);
  k_attn<<<240, 320, 0, stream>>>(Qf, Kf, Vt, AttO);
  k_gemm<0><<<300, 256, 0, stream>>>(AttO, WoT, bo, d_out, DIM, DIM, SEQ, 12);
}

// Round 15
// 236.921 us; speedup vs baseline: 1.4600x; 1.0367x over previous
//
#include <hip/hip_runtime.h>
#include <cstdint>

#define SEQ     3120
#define SPAD    3200
#define DIM     1536
#define NQKV    4608
#define HEADS   12
#define HD      128
#define SPATIAL 390
#define EPSV    1e-5f
#define KVBLK   64
#define NTILES  49
#define NEGBIG  (-1e30f)
// 1/sqrt(128) * log2(e): attention scores computed in log2 domain.
// FIXED-scale softmax (no running max): |s| <= ~12 in log2 domain, so
// exp2(s) <= 4096 and sum <= ~1e7 -- safely inside fp32; softmax is exactly
// scale-invariant, and bf16 relative precision is scale-free.
#define QSCALE  (0.08838834764831845f * 1.4426950408889634f)
#define CROW(r, hi) ((((r) & 3) + 8 * ((r) >> 2)) + 4 * (hi))

typedef unsigned short u16;
typedef short s16x8 __attribute__((ext_vector_type(8)));
typedef float f32x4 __attribute__((ext_vector_type(4)));
typedef float f32x16 __attribute__((ext_vector_type(16)));

__device__ __forceinline__ u16 f2bf(float f) {
  union { float f; unsigned u; } v; v.f = f;
  unsigned r = v.u + 0x7FFFu + ((v.u >> 16) & 1u);
  return (u16)(r >> 16);
}
__device__ __forceinline__ float bf2f(u16 b) {
  union { unsigned u; float f; } v; v.u = ((unsigned)b) << 16;
  return v.f;
}
__device__ __forceinline__ unsigned cvtpk(float lo, float hi) {
  unsigned r;
  asm("v_cvt_pk_bf16_f32 %0, %1, %2" : "=v"(r) : "v"(lo), "v"(hi));
  return r;
}
// async global->LDS, 16B per lane. LDS dest = wave-uniform base + lane*16.
__device__ __forceinline__ void gload16(const void* g, const void* l) {
  __builtin_amdgcn_global_load_lds(
      (const __attribute__((address_space(1))) unsigned*)g,
      (__attribute__((address_space(3))) unsigned*)(uintptr_t)l,
      16, 0, 0);
}

// ------- 1+2 fused prep: blocks [0,4800) convert x + biascat; -------------
//         blocks [4800,7104) transpose+convert the 4 weight matrices.
__global__ __launch_bounds__(256) void k_prep(
    const float* __restrict__ x, const float* __restrict__ bq,
    const float* __restrict__ bk, const float* __restrict__ bv,
    const float* __restrict__ Wq, const float* __restrict__ Wk,
    const float* __restrict__ Wv, const float* __restrict__ Wo,
    u16* __restrict__ xb, float* __restrict__ bcat,
    u16* __restrict__ WtAll, u16* __restrict__ WoT) {
  __shared__ float t[64][65];
  const int bid = blockIdx.x;
  if (bid < 4800) {
    // ---- convert x fp32 -> bf16, pad rows [SEQ,SPAD) with 0; biascat -----
    if (bid == 0) {
      for (int j = threadIdx.x; j < NQKV; j += 256)
        bcat[j] = (j < DIM) ? bq[j] : (j < 2 * DIM) ? bk[j - DIM] : bv[j - 2 * DIM];
    }
    const int i = (bid * 256 + threadIdx.x) * 4;
    if (i >= SPAD * DIM) return;
    const int row = i / DIM;
    float4 v = make_float4(0.f, 0.f, 0.f, 0.f);
    if (row < SEQ) v = *(const float4*)(x + i);
    const unsigned lo = (unsigned)f2bf(v.x) | ((unsigned)f2bf(v.y) << 16);
    const unsigned hi = (unsigned)f2bf(v.z) | ((unsigned)f2bf(v.w) << 16);
    *(uint2*)(xb + i) = make_uint2(lo, hi);
  } else {
    // ---- transpose weights: Wt[n][k] = W[k][n], 64x64 tiles --------------
    const int tb = bid - 4800;              // 0..2303
    const int wsel = tb / 576;              // 576 = 24*24
    const int rem = tb - wsel * 576;
    const int byi = rem / 24, bxi = rem - (rem / 24) * 24;
    const float* W = (wsel == 0) ? Wq : (wsel == 1) ? Wk : (wsel == 2) ? Wv : Wo;
    const int k0 = bxi * 64, n0 = byi * 64;
    const int c = threadIdx.x & 63, r4 = threadIdx.x >> 6;
#pragma unroll
    for (int rr = 0; rr < 64; rr += 4)
      t[r4 + rr][c] = W[(size_t)(k0 + r4 + rr) * DIM + n0 + c];
    __syncthreads();
    u16* Wt = (wsel < 3) ? (WtAll + (size_t)wsel * DIM * DIM) : WoT;
    const int kp = threadIdx.x & 31;
    const int r8 = threadIdx.x >> 5;
#pragma unroll
    for (int rr = 0; rr < 64; rr += 8) {
      const int n = r8 + rr;
      const unsigned v = (unsigned)f2bf(t[2 * kp][n]) |
                         ((unsigned)f2bf(t[2 * kp + 1][n]) << 16);
      *(unsigned*)&Wt[(size_t)(n0 + n) * DIM + k0 + 2 * kp] = v;
    }
  }
}

// ------- 4/8. bf16 MFMA GEMM, BK=64, dbuf + counted vmcnt (attn pattern) --
template <int OUT_BF16>
__global__ __launch_bounds__(256) void k_gemm(const u16* __restrict__ A,
                                              const u16* __restrict__ Bt,
                                              const float* __restrict__ bias,
                                              void* __restrict__ Cout,
                                              int N, int K, int storeMmax,
                                              int nbx) {
  __shared__ short As[2][8192];  // [128][64] swizzled
  __shared__ short Bs[2][8192];
  const int nwg = gridDim.x;
  const int q = nwg >> 3, r = nwg & 7;
  const int xcd = blockIdx.x & 7, idx = blockIdx.x >> 3;
  const int swz = (xcd < r ? xcd * (q + 1) : r * (q + 1) + (xcd - r) * q) + idx;
  const int bxi = swz % nbx, byi = swz / nbx;
  const int brow = byi * 128, bcol = bxi * 128;

  const int tid = threadIdx.x;
  const int lane = tid & 63, wv = tid >> 6;
  const int l15 = lane & 15, g = lane >> 4;
  const int wr = wv >> 1, wc = wv & 1;

  const f32x4 z4 = {0.f, 0.f, 0.f, 0.f};
  f32x4 acc[4][4];
#pragma unroll
  for (int m = 0; m < 4; ++m)
#pragma unroll
    for (int n = 0; n < 4; ++n) acc[m][n] = z4;

  const u16* Ap[4];
  const u16* Bp[4];
  const int sch = ((lane & 7) ^ ((lane >> 3) & 7)) * 8;
#pragma unroll
  for (int it = 0; it < 4; ++it) {
    const int row = it * 32 + wv * 8 + (lane >> 3);
    Ap[it] = A + (size_t)(brow + row) * K + sch;
    Bp[it] = Bt + (size_t)(bcol + row) * K + sch;
  }
  auto stage = [&](int T, int B) {
    const int k0 = T * 64;
#pragma unroll
    for (int it = 0; it < 4; ++it) {
      gload16(Ap[it] + k0, &As[B][(it * 32 + wv * 8) * 64]);
      gload16(Bp[it] + k0, &Bs[B][(it * 32 + wv * 8) * 64]);
    }
  };

  const int NK = K >> 6;
  stage(0, 0);

  for (int t = 0; t < NK; ++t) {
    const int b = t & 1;
    if (t + 1 < NK) {
      stage(t + 1, b ^ 1);
      asm volatile("s_waitcnt vmcnt(8)" ::: "memory");  // tile t's 8 done
    } else {
      asm volatile("s_waitcnt vmcnt(0)" ::: "memory");
    }
    __builtin_amdgcn_s_barrier();
    __builtin_amdgcn_sched_barrier(0);
#pragma unroll
    for (int kk = 0; kk < 2; ++kk) {
      s16x8 a[4], bfr[4];
#pragma unroll
      for (int m = 0; m < 4; ++m)
        a[m] = *(const s16x8*)&As[b][(wr * 64 + m * 16 + l15) * 64 +
                                     (((kk * 4 + g) ^ (l15 & 7)) * 8)];
#pragma unroll
      for (int n = 0; n < 4; ++n)
        bfr[n] = *(const s16x8*)&Bs[b][(wc * 64 + n * 16 + l15) * 64 +
                                       (((kk * 4 + g) ^ (l15 & 7)) * 8)];
#pragma unroll
      for (int m = 0; m < 4; ++m)
#pragma unroll
        for (int n = 0; n < 4; ++n)
          acc[m][n] = __builtin_amdgcn_mfma_f32_16x16x32_bf16(a[m], bfr[n], acc[m][n], 0, 0, 0);
    }
    __builtin_amdgcn_s_barrier();  // protect buf b before stage(t+2) writes it
    __builtin_amdgcn_sched_barrier(0);
  }

#pragma unroll
  for (int m = 0; m < 4; ++m) {
#pragma unroll
    for (int n = 0; n < 4; ++n) {
      const int cc = bcol + wc * 64 + n * 16 + l15;
      const float bb = bias[cc];
#pragma unroll
      for (int i = 0; i < 4; ++i) {
        const int rr = brow + wr * 64 + m * 16 + g * 4 + i;
        if (rr < storeMmax) {
          const float v = acc[m][n][i] + bb;
          if (OUT_BF16) ((u16*)Cout)[(size_t)rr * N + cc] = f2bf(v);
          else          ((float*)Cout)[(size_t)rr * N + cc] = v;
        }
      }
    }
  }
}

// ---------------- 5. per-token: rmsnorm + rope + biases (vectorized) -------
__global__ __launch_bounds__(256) void k_post(
    const u16* __restrict__ Pqkv, const float* __restrict__ freqs,
    const float* __restrict__ gq, const float* __restrict__ gk,
    const float* __restrict__ qkfb, const float* __restrict__ vfb,
    const float* __restrict__ vsb,
    u16* __restrict__ Qf, u16* __restrict__ Kf, u16* __restrict__ Vf) {
  const int s = blockIdx.x;
  const int t = threadIdx.x;
  const int fidx = s / SPATIAL;
  const int sp = s - fidx * SPATIAL;
  __shared__ float cs[64], sn[64];
  __shared__ float red[8];
  if (t < 64) {
    const float a = freqs[s * 64 + t];
    cs[t] = __cosf(a);
    sn[t] = __sinf(a);
  }
  const u16* qrow = Pqkv + (size_t)s * NQKV;
  const u16* krow = qrow + DIM;
  const u16* vrow = qrow + 2 * DIM;
  s16x8 q8, k8, v8;
  float sq = 0.f, sk = 0.f;
  if (t < 192) {
    q8 = *(const s16x8*)(qrow + 8 * t);
    k8 = *(const s16x8*)(krow + 8 * t);
    v8 = *(const s16x8*)(vrow + 8 * t);
#pragma unroll
    for (int i = 0; i < 8; ++i) {
      const float a = bf2f((u16)q8[i]); sq += a * a;
      const float b = bf2f((u16)k8[i]); sk += b * b;
    }
  }
#pragma unroll
  for (int off = 1; off < 64; off <<= 1) {
    sq += __shfl_xor(sq, off);
    sk += __shfl_xor(sk, off);
  }
  const int lane = t & 63, wv = t >> 6;
  if (lane == 0) { red[wv] = sq; red[wv + 4] = sk; }
  __syncthreads();
  sq = red[0] + red[1] + red[2] + red[3];
  sk = red[4] + red[5] + red[6] + red[7];
  const float rq = rsqrtf(sq * (1.0f / DIM) + EPSV);
  const float rk = rsqrtf(sk * (1.0f / DIM) + EPSV);
  if (t >= 192) return;
  const int d0 = 8 * t;
  float GQ[8], GK[8], FB[8], VF[8], VS[8];
  *(float4*)&GQ[0] = *(const float4*)(gq + d0);
  *(float4*)&GQ[4] = *(const float4*)(gq + d0 + 4);
  *(float4*)&GK[0] = *(const float4*)(gk + d0);
  *(float4*)&GK[4] = *(const float4*)(gk + d0 + 4);
  *(float4*)&FB[0] = *(const float4*)(qkfb + fidx * DIM + d0);
  *(float4*)&FB[4] = *(const float4*)(qkfb + fidx * DIM + d0 + 4);
  *(float4*)&VF[0] = *(const float4*)(vfb + fidx * DIM + d0);
  *(float4*)&VF[4] = *(const float4*)(vfb + fidx * DIM + d0 + 4);
  *(float4*)&VS[0] = *(const float4*)(vsb + (size_t)sp * DIM + d0);
  *(float4*)&VS[4] = *(const float4*)(vsb + (size_t)sp * DIM + d0 + 4);
  unsigned qo[4], ko[4], vo[4];
#pragma unroll
  for (int pi = 0; pi < 4; ++pi) {
    const int pin = (4 * t + pi) & 63;
    const float c = cs[pin], s_ = sn[pin];
    float xr = bf2f((u16)q8[2 * pi]) * rq * GQ[2 * pi];
    float xi = bf2f((u16)q8[2 * pi + 1]) * rq * GQ[2 * pi + 1];
    const float q0 = (xr * c - xi * s_ + FB[2 * pi]) * QSCALE;
    const float q1 = (xr * s_ + xi * c + FB[2 * pi + 1]) * QSCALE;
    qo[pi] = (unsigned)f2bf(q0) | ((unsigned)f2bf(q1) << 16);
    xr = bf2f((u16)k8[2 * pi]) * rk * GK[2 * pi];
    xi = bf2f((u16)k8[2 * pi + 1]) * rk * GK[2 * pi + 1];
    const float kk0 = xr * c - xi * s_ + FB[2 * pi];
    const float kk1 = xr * s_ + xi * c + FB[2 * pi + 1];
    ko[pi] = (unsigned)f2bf(kk0) | ((unsigned)f2bf(kk1) << 16);
    const float v0 = bf2f((u16)v8[2 * pi]) + VF[2 * pi] + VS[2 * pi];
    const float v1 = bf2f((u16)v8[2 * pi + 1]) + VF[2 * pi + 1] + VS[2 * pi + 1];
    vo[pi] = (unsigned)f2bf(v0) | ((unsigned)f2bf(v1) << 16);
  }
  *(uint4*)(Qf + (size_t)s * DIM + d0) = make_uint4(qo[0], qo[1], qo[2], qo[3]);
  *(uint4*)(Kf + (size_t)s * DIM + d0) = make_uint4(ko[0], ko[1], ko[2], ko[3]);
  *(uint4*)(Vf + (size_t)s * DIM + d0) = make_uint4(vo[0], vo[1], vo[2], vo[3]);
}

// ---------------- 6. V transpose: Vf[s][1536] -> Vt[dglob][SPAD] -----------
__global__ __launch_bounds__(256) void k_transpose_v(const u16* __restrict__ Vf,
                                                     u16* __restrict__ Vt) {
  __shared__ u16 tile[64][65];
  const int s0 = blockIdx.x * 64, c0 = blockIdx.y * 64;
  const int c = threadIdx.x & 63, r4 = threadIdx.x >> 6;
#pragma unroll
  for (int rr = 0; rr < 64; rr += 4) {
    const int s = s0 + r4 + rr;
    tile[r4 + rr][c] = (s < SEQ) ? Vf[(size_t)s * DIM + c0 + c] : (u16)0;
  }
  __syncthreads();
#pragma unroll
  for (int rr = 0; rr < 64; rr += 4) {
    const int dglob = c0 + r4 + rr;
    Vt[(size_t)dglob * SPAD + s0 + c] = tile[c][r4 + rr];
  }
}

// ---------------- 7. flash attention (R8 + XCD grouping + permlane) --------
// 1D grid 240: gb = (bid&7)*30 + (bid>>3); h = gb/20, bx = gb%20 (R13:
// FETCH 80->18MB). P partner-exchange now via v_permlane32_swap_b32 (VALU)
// instead of 16 ds_bpermute/tile (LDS pipe): for the PV A-operand,
// (pw[0],pw[2]) = swap(W[b+0],W[b+2]), (pw[1],pw[3]) = swap(W[b+1],W[b+3])
// -- bit-identical values, ~25% less LDS-pipe traffic, -16 VGPR (X[] gone).
__global__ __launch_bounds__(320, 2) void k_attn(const u16* __restrict__ Qf,
                                                 const u16* __restrict__ Kf,
                                                 const u16* __restrict__ Vt,
                                                 u16* __restrict__ AttO) {
  __shared__ short Ks[2][8192];  // [64 key][16 chunk][8]
  __shared__ short Vs[2][8192];  // [128 d][8 chunk][8]
  const int bid = blockIdx.x;
  const int gb = (bid & 7) * 30 + (bid >> 3);
  const int h = gb / 20;
  const int bx = gb - h * 20;
  const int tid = threadIdx.x;
  const int lane = tid & 63, w = tid >> 6;     // w in 0..4
  const int l31 = lane & 31, hi = lane >> 5;
  const int qrow = bx * 160 + w * 32 + l31;

  // Q B-frags: qb[s] = Q[qrow][16s + 8hi + j]
  s16x8 qb[8];
  {
    const u16* qp = Qf + (size_t)qrow * DIM + h * HD + hi * 8;
#pragma unroll
    for (int s = 0; s < 8; ++s) qb[s] = *(const s16x8*)(qp + s * 16);
  }

  f32x16 o[4];
#pragma unroll
  for (int d = 0; d < 4; ++d)
#pragma unroll
    for (int r = 0; r < 16; ++r) o[d][r] = 0.f;
  float sl = 0.f;

  // staging pointers (warps 0..3 only)
  const u16* Kp[4];
  const u16* Vp[4];
  if (w < 4) {
#pragma unroll
    for (int it = 0; it < 4; ++it) {
      const int krow = w * 16 + it * 4 + (lane >> 4);
      const int kch = (lane & 15) ^ (it * 4 + (lane >> 4));
      Kp[it] = Kf + (size_t)krow * DIM + h * HD + kch * 8;
      const int vrow = w * 32 + it * 8 + (lane >> 3);
      const int vch = (lane & 7) ^ (lane >> 3);
      Vp[it] = Vt + (size_t)(h * HD + vrow) * SPAD + vch * 8;
    }
  }
  auto stage = [&](int T, int B) {
    const size_t kof = (size_t)T * KVBLK * DIM;
    const int vof = T * KVBLK;
#pragma unroll
    for (int it = 0; it < 4; ++it) {
      gload16(Kp[it] + kof, &Ks[B][(w * 16 + it * 4) * 128]);
      gload16(Vp[it] + vof, &Vs[B][(w * 32 + it * 8) * 64]);
    }
  };

  if (w < 4) {
    asm volatile("s_waitcnt vmcnt(0)" ::: "memory");
    stage(0, 0);
  }

  for (int t = 0; t < NTILES; ++t) {
    const int b = t & 1;
    if (w < 4) {
      if (t + 1 < NTILES) {
        stage(t + 1, b ^ 1);
        asm volatile("s_waitcnt vmcnt(8)" ::: "memory");
      } else {
        asm volatile("s_waitcnt vmcnt(0)" ::: "memory");
      }
    }
    __builtin_amdgcn_s_barrier();
    __builtin_amdgcn_sched_barrier(0);

    // S^T = K Q  (D[key][q]: col q = l31, row key = CROW(r,hi) per grp of 32)
    f32x16 st[2];
#pragma unroll
    for (int r = 0; r < 16; ++r) { st[0][r] = 0.f; st[1][r] = 0.f; }
    __builtin_amdgcn_s_setprio(1);
#pragma unroll
    for (int grp = 0; grp < 2; ++grp)
#pragma unroll
      for (int s = 0; s < 8; ++s) {
        const s16x8 ka = *(const s16x8*)&Ks[b][(grp * 32 + l31) * 128 +
                                              (((2 * s + hi) ^ (lane & 15)) * 8)];
        st[grp] = __builtin_amdgcn_mfma_f32_32x32x16_bf16(ka, qb[s], st[grp], 0, 0, 0);
      }
    __builtin_amdgcn_s_setprio(0);

    // hoist V B-frags (ds_read latency hides under softmax VALU)
    s16x8 vb[4][4];
#pragma unroll
    for (int s = 0; s < 4; ++s)
#pragma unroll
      for (int d = 0; d < 4; ++d)
        vb[s][d] = *(const s16x8*)&Vs[b][(d * 32 + l31) * 64 +
                                         (((2 * s + hi) ^ (lane & 7)) * 8)];

    if (t == NTILES - 1) {  // keys 3120..3135 invalid: grp1 regs 8..15
#pragma unroll
      for (int r = 8; r < 16; ++r) st[1][r] = NEGBIG;  // exp2 -> 0
    }
    // P = exp2(S): fixed scale, lane-local sums, pack bf16
    unsigned W[16];
    float p0s = 0.f, p1s = 0.f, p2s = 0.f, p3s = 0.f;
#pragma unroll
    for (int grp = 0; grp < 2; ++grp)
#pragma unroll
      for (int i = 0; i < 8; ++i) {
        const float p0 = exp2f(st[grp][2 * i]);
        const float p1 = exp2f(st[grp][2 * i + 1]);
        if (grp) { p2s += p0; p3s += p1; } else { p0s += p0; p1s += p1; }
        W[grp * 8 + i] = cvtpk(p0, p1);
      }
    sl += (p0s + p1s) + (p2s + p3s);

    // O += P V  (partner exchange via permlane32_swap, VALU not LDS)
    __builtin_amdgcn_s_setprio(1);
#pragma unroll
    for (int s = 0; s < 4; ++s) {
      const int base = (s >> 1) * 8 + (s & 1) * 4;
      unsigned a0 = W[base + 0], b0 = W[base + 2];
      unsigned a1 = W[base + 1], b1 = W[base + 3];
      asm volatile("v_permlane32_swap_b32 %0, %1" : "+v"(a0), "+v"(b0));
      asm volatile("v_permlane32_swap_b32 %0, %1" : "+v"(a1), "+v"(b1));
      unsigned pw[4] = {a0, a1, b0, b1};
      const s16x8 pa = *(const s16x8*)pw;
#pragma unroll
      for (int d = 0; d < 4; ++d)
        o[d] = __builtin_amdgcn_mfma_f32_32x32x16_bf16(pa, vb[s][d], o[d], 0, 0, 0);
    }
    __builtin_amdgcn_s_setprio(0);
    __builtin_amdgcn_s_barrier();
    __builtin_amdgcn_sched_barrier(0);
  }

  sl += __shfl_xor(sl, 32);
  const float rs = 1.0f / sl;
#pragma unroll
  for (int r = 0; r < 16; ++r) {
    const float rq = __shfl(rs, CROW(r, hi));
    const int row = bx * 160 + w * 32 + CROW(r, hi);
    if (row < SEQ) {
#pragma unroll
      for (int d = 0; d < 4; ++d)
        AttO[(size_t)row * DIM + h * HD + d * 32 + l31] = f2bf(o[d][r] * rq);
    }
  }
}

// ---------------------------------------------------------------------------
extern "C" void kernel_launch(void* const* d_in, const int* in_sizes, int n_in,
                              void* d_out, int out_size, void* d_ws, size_t ws_size,
                              hipStream_t stream) {
  const float* x    = (const float*)d_in[0];
  const float* freqs= (const float*)d_in[1];
  const float* Wq   = (const float*)d_in[2];
  const float* bq   = (const float*)d_in[3];
  const float* gq   = (const float*)d_in[4];
  const float* Wk   = (const float*)d_in[5];
  const float* bk   = (const float*)d_in[6];
  const float* gk   = (const float*)d_in[7];
  const float* Wv   = (const float*)d_in[8];
  const float* bv   = (const float*)d_in[9];
  const float* Wo   = (const float*)d_in[10];
  const float* bo   = (const float*)d_in[11];
  const float* qkfb = (const float*)d_in[12];
  const float* vfb  = (const float*)d_in[13];
  const float* vsb  = (const float*)d_in[14];

  if (ws_size < (size_t)87705600) return;

  char* ws = (char*)d_ws;
  u16*   xb    = (u16*)(ws);               // [3200][1536] bf16
  u16*   Vt    = (u16*)(ws);               // alias: xb dead after QKV GEMM
  u16*   WtAll = (u16*)(ws + 9830400);     // [4608][1536] bf16 (Wq|Wk|Wv)^T
  u16*   WoT   = (u16*)(ws + 23986176);    // [1536][1536] bf16 Wo^T
  float* bcat  = (float*)(ws + 28704768);  // [4608]
  u16*   Pqkv  = (u16*)(ws + 28723200);    // [3200][4608] bf16
  u16*   AttO  = (u16*)(ws + 28723200);    // alias: Pqkv dead after k_post
  u16*   Qf    = (u16*)(ws + 58214400);    // [3200][1536] bf16
  u16*   Kf    = (u16*)(ws + 68044800);    // [3200][1536] bf16
  u16*   Vf    = (u16*)(ws + 77875200);    // [3200][1536] bf16

  k_prep<<<7104, 256, 0, stream>>>(x, bq, bk, bv, Wq, Wk, Wv, Wo,
                                   xb, bcat, WtAll, WoT);
  k_gemm<1><<<900, 256, 0, stream>>>(xb, WtAll, bcat, Pqkv, NQKV, DIM, SPAD, 36);
  k_post<<<SEQ, 256, 0, stream>>>(Pqkv, freqs, gq, gk, qkfb, vfb, vsb, Qf, Kf, Vf);
  k_transpose_v<<<dim3(50, 24), 256, 0, stream>>>(Vf, Vt);
  k_attn<<<240, 320, 0, stream>>>(Qf, Kf, Vt, AttO);
  k_gemm<0><<<300, 256, 0, stream>>>(AttO, WoT, bo, d_out, DIM, DIM, SEQ, 12);
}

// Round 16
// 232.300 us; speedup vs baseline: 1.4890x; 1.0199x over previous
//
#include <hip/hip_runtime.h>
#include <cstdint>

#define SEQ     3120
#define SPAD    3200
#define DIM     1536
#define NQKV    4608
#define HEADS   12
#define HD      128
#define SPATIAL 390
#define EPSV    1e-5f
#define KVBLK   128
#define NTILES  25
#define NEGBIG  (-1e30f)
// 1/sqrt(128) * log2(e): attention scores computed in log2 domain.
// FIXED-scale softmax (no running max): |s| <= ~12 in log2 domain, so
// exp2(s) <= 4096 and sum <= ~1e7 -- safely inside fp32; softmax is exactly
// scale-invariant, and bf16 relative precision is scale-free.
#define QSCALE  (0.08838834764831845f * 1.4426950408889634f)
#define CROW(r, hi) ((((r) & 3) + 8 * ((r) >> 2)) + 4 * (hi))

typedef unsigned short u16;
typedef short s16x8 __attribute__((ext_vector_type(8)));
typedef float f32x4 __attribute__((ext_vector_type(4)));
typedef float f32x16 __attribute__((ext_vector_type(16)));

__device__ __forceinline__ u16 f2bf(float f) {
  union { float f; unsigned u; } v; v.f = f;
  unsigned r = v.u + 0x7FFFu + ((v.u >> 16) & 1u);
  return (u16)(r >> 16);
}
__device__ __forceinline__ float bf2f(u16 b) {
  union { unsigned u; float f; } v; v.u = ((unsigned)b) << 16;
  return v.f;
}
__device__ __forceinline__ unsigned cvtpk(float lo, float hi) {
  unsigned r;
  asm("v_cvt_pk_bf16_f32 %0, %1, %2" : "=v"(r) : "v"(lo), "v"(hi));
  return r;
}
// async global->LDS, 16B per lane. LDS dest = wave-uniform base + lane*16.
__device__ __forceinline__ void gload16(const void* g, const void* l) {
  __builtin_amdgcn_global_load_lds(
      (const __attribute__((address_space(1))) unsigned*)g,
      (__attribute__((address_space(3))) unsigned*)(uintptr_t)l,
      16, 0, 0);
}

// ------- 1+2 fused prep: blocks [0,4800) convert x + biascat; -------------
//         blocks [4800,7104) transpose+convert the 4 weight matrices.
__global__ __launch_bounds__(256) void k_prep(
    const float* __restrict__ x, const float* __restrict__ bq,
    const float* __restrict__ bk, const float* __restrict__ bv,
    const float* __restrict__ Wq, const float* __restrict__ Wk,
    const float* __restrict__ Wv, const float* __restrict__ Wo,
    u16* __restrict__ xb, float* __restrict__ bcat,
    u16* __restrict__ WtAll, u16* __restrict__ WoT) {
  __shared__ float t[64][65];
  const int bid = blockIdx.x;
  if (bid < 4800) {
    // ---- convert x fp32 -> bf16, pad rows [SEQ,SPAD) with 0; biascat -----
    if (bid == 0) {
      for (int j = threadIdx.x; j < NQKV; j += 256)
        bcat[j] = (j < DIM) ? bq[j] : (j < 2 * DIM) ? bk[j - DIM] : bv[j - 2 * DIM];
    }
    const int i = (bid * 256 + threadIdx.x) * 4;
    if (i >= SPAD * DIM) return;
    const int row = i / DIM;
    float4 v = make_float4(0.f, 0.f, 0.f, 0.f);
    if (row < SEQ) v = *(const float4*)(x + i);
    const unsigned lo = (unsigned)f2bf(v.x) | ((unsigned)f2bf(v.y) << 16);
    const unsigned hi = (unsigned)f2bf(v.z) | ((unsigned)f2bf(v.w) << 16);
    *(uint2*)(xb + i) = make_uint2(lo, hi);
  } else {
    // ---- transpose weights: Wt[n][k] = W[k][n], 64x64 tiles --------------
    const int tb = bid - 4800;              // 0..2303
    const int wsel = tb / 576;              // 576 = 24*24
    const int rem = tb - wsel * 576;
    const int byi = rem / 24, bxi = rem - (rem / 24) * 24;
    const float* W = (wsel == 0) ? Wq : (wsel == 1) ? Wk : (wsel == 2) ? Wv : Wo;
    const int k0 = bxi * 64, n0 = byi * 64;
    const int c = threadIdx.x & 63, r4 = threadIdx.x >> 6;
#pragma unroll
    for (int rr = 0; rr < 64; rr += 4)
      t[r4 + rr][c] = W[(size_t)(k0 + r4 + rr) * DIM + n0 + c];
    __syncthreads();
    u16* Wt = (wsel < 3) ? (WtAll + (size_t)wsel * DIM * DIM) : WoT;
    const int kp = threadIdx.x & 31;
    const int r8 = threadIdx.x >> 5;
#pragma unroll
    for (int rr = 0; rr < 64; rr += 8) {
      const int n = r8 + rr;
      const unsigned v = (unsigned)f2bf(t[2 * kp][n]) |
                         ((unsigned)f2bf(t[2 * kp + 1][n]) << 16);
      *(unsigned*)&Wt[(size_t)(n0 + n) * DIM + k0 + 2 * kp] = v;
    }
  }
}

// ------- 4/8. bf16 MFMA GEMM, BK=64, dbuf + counted vmcnt (attn pattern) --
template <int OUT_BF16>
__global__ __launch_bounds__(256) void k_gemm(const u16* __restrict__ A,
                                              const u16* __restrict__ Bt,
                                              const float* __restrict__ bias,
                                              void* __restrict__ Cout,
                                              int N, int K, int storeMmax,
                                              int nbx) {
  __shared__ short As[2][8192];  // [128][64] swizzled
  __shared__ short Bs[2][8192];
  const int nwg = gridDim.x;
  const int q = nwg >> 3, r = nwg & 7;
  const int xcd = blockIdx.x & 7, idx = blockIdx.x >> 3;
  const int swz = (xcd < r ? xcd * (q + 1) : r * (q + 1) + (xcd - r) * q) + idx;
  const int bxi = swz % nbx, byi = swz / nbx;
  const int brow = byi * 128, bcol = bxi * 128;

  const int tid = threadIdx.x;
  const int lane = tid & 63, wv = tid >> 6;
  const int l15 = lane & 15, g = lane >> 4;
  const int wr = wv >> 1, wc = wv & 1;

  const f32x4 z4 = {0.f, 0.f, 0.f, 0.f};
  f32x4 acc[4][4];
#pragma unroll
  for (int m = 0; m < 4; ++m)
#pragma unroll
    for (int n = 0; n < 4; ++n) acc[m][n] = z4;

  const u16* Ap[4];
  const u16* Bp[4];
  const int sch = ((lane & 7) ^ ((lane >> 3) & 7)) * 8;
#pragma unroll
  for (int it = 0; it < 4; ++it) {
    const int row = it * 32 + wv * 8 + (lane >> 3);
    Ap[it] = A + (size_t)(brow + row) * K + sch;
    Bp[it] = Bt + (size_t)(bcol + row) * K + sch;
  }
  auto stage = [&](int T, int B) {
    const int k0 = T * 64;
#pragma unroll
    for (int it = 0; it < 4; ++it) {
      gload16(Ap[it] + k0, &As[B][(it * 32 + wv * 8) * 64]);
      gload16(Bp[it] + k0, &Bs[B][(it * 32 + wv * 8) * 64]);
    }
  };

  const int NK = K >> 6;
  stage(0, 0);

  for (int t = 0; t < NK; ++t) {
    const int b = t & 1;
    if (t + 1 < NK) {
      stage(t + 1, b ^ 1);
      asm volatile("s_waitcnt vmcnt(8)" ::: "memory");  // tile t's 8 done
    } else {
      asm volatile("s_waitcnt vmcnt(0)" ::: "memory");
    }
    __builtin_amdgcn_s_barrier();
    __builtin_amdgcn_sched_barrier(0);
#pragma unroll
    for (int kk = 0; kk < 2; ++kk) {
      s16x8 a[4], bfr[4];
#pragma unroll
      for (int m = 0; m < 4; ++m)
        a[m] = *(const s16x8*)&As[b][(wr * 64 + m * 16 + l15) * 64 +
                                     (((kk * 4 + g) ^ (l15 & 7)) * 8)];
#pragma unroll
      for (int n = 0; n < 4; ++n)
        bfr[n] = *(const s16x8*)&Bs[b][(wc * 64 + n * 16 + l15) * 64 +
                                       (((kk * 4 + g) ^ (l15 & 7)) * 8)];
#pragma unroll
      for (int m = 0; m < 4; ++m)
#pragma unroll
        for (int n = 0; n < 4; ++n)
          acc[m][n] = __builtin_amdgcn_mfma_f32_16x16x32_bf16(a[m], bfr[n], acc[m][n], 0, 0, 0);
    }
    __builtin_amdgcn_s_barrier();  // protect buf b before stage(t+2) writes it
    __builtin_amdgcn_sched_barrier(0);
  }

#pragma unroll
  for (int m = 0; m < 4; ++m) {
#pragma unroll
    for (int n = 0; n < 4; ++n) {
      const int cc = bcol + wc * 64 + n * 16 + l15;
      const float bb = bias[cc];
#pragma unroll
      for (int i = 0; i < 4; ++i) {
        const int rr = brow + wr * 64 + m * 16 + g * 4 + i;
        if (rr < storeMmax) {
          const float v = acc[m][n][i] + bb;
          if (OUT_BF16) ((u16*)Cout)[(size_t)rr * N + cc] = f2bf(v);
          else          ((float*)Cout)[(size_t)rr * N + cc] = v;
        }
      }
    }
  }
}

// ---------------- 5. per-token: rmsnorm + rope + biases (vectorized) -------
__global__ __launch_bounds__(256) void k_post(
    const u16* __restrict__ Pqkv, const float* __restrict__ freqs,
    const float* __restrict__ gq, const float* __restrict__ gk,
    const float* __restrict__ qkfb, const float* __restrict__ vfb,
    const float* __restrict__ vsb,
    u16* __restrict__ Qf, u16* __restrict__ Kf, u16* __restrict__ Vf) {
  const int s = blockIdx.x;
  const int t = threadIdx.x;
  const int fidx = s / SPATIAL;
  const int sp = s - fidx * SPATIAL;
  __shared__ float cs[64], sn[64];
  __shared__ float red[8];
  if (t < 64) {
    const float a = freqs[s * 64 + t];
    cs[t] = __cosf(a);
    sn[t] = __sinf(a);
  }
  const u16* qrow = Pqkv + (size_t)s * NQKV;
  const u16* krow = qrow + DIM;
  const u16* vrow = qrow + 2 * DIM;
  s16x8 q8, k8, v8;
  float sq = 0.f, sk = 0.f;
  if (t < 192) {
    q8 = *(const s16x8*)(qrow + 8 * t);
    k8 = *(const s16x8*)(krow + 8 * t);
    v8 = *(const s16x8*)(vrow + 8 * t);
#pragma unroll
    for (int i = 0; i < 8; ++i) {
      const float a = bf2f((u16)q8[i]); sq += a * a;
      const float b = bf2f((u16)k8[i]); sk += b * b;
    }
  }
#pragma unroll
  for (int off = 1; off < 64; off <<= 1) {
    sq += __shfl_xor(sq, off);
    sk += __shfl_xor(sk, off);
  }
  const int lane = t & 63, wv = t >> 6;
  if (lane == 0) { red[wv] = sq; red[wv + 4] = sk; }
  __syncthreads();
  sq = red[0] + red[1] + red[2] + red[3];
  sk = red[4] + red[5] + red[6] + red[7];
  const float rq = rsqrtf(sq * (1.0f / DIM) + EPSV);
  const float rk = rsqrtf(sk * (1.0f / DIM) + EPSV);
  if (t >= 192) return;
  const int d0 = 8 * t;
  float GQ[8], GK[8], FB[8], VF[8], VS[8];
  *(float4*)&GQ[0] = *(const float4*)(gq + d0);
  *(float4*)&GQ[4] = *(const float4*)(gq + d0 + 4);
  *(float4*)&GK[0] = *(const float4*)(gk + d0);
  *(float4*)&GK[4] = *(const float4*)(gk + d0 + 4);
  *(float4*)&FB[0] = *(const float4*)(qkfb + fidx * DIM + d0);
  *(float4*)&FB[4] = *(const float4*)(qkfb + fidx * DIM + d0 + 4);
  *(float4*)&VF[0] = *(const float4*)(vfb + fidx * DIM + d0);
  *(float4*)&VF[4] = *(const float4*)(vfb + fidx * DIM + d0 + 4);
  *(float4*)&VS[0] = *(const float4*)(vsb + (size_t)sp * DIM + d0);
  *(float4*)&VS[4] = *(const float4*)(vsb + (size_t)sp * DIM + d0 + 4);
  unsigned qo[4], ko[4], vo[4];
#pragma unroll
  for (int pi = 0; pi < 4; ++pi) {
    const int pin = (4 * t + pi) & 63;
    const float c = cs[pin], s_ = sn[pin];
    float xr = bf2f((u16)q8[2 * pi]) * rq * GQ[2 * pi];
    float xi = bf2f((u16)q8[2 * pi + 1]) * rq * GQ[2 * pi + 1];
    const float q0 = (xr * c - xi * s_ + FB[2 * pi]) * QSCALE;
    const float q1 = (xr * s_ + xi * c + FB[2 * pi + 1]) * QSCALE;
    qo[pi] = (unsigned)f2bf(q0) | ((unsigned)f2bf(q1) << 16);
    xr = bf2f((u16)k8[2 * pi]) * rk * GK[2 * pi];
    xi = bf2f((u16)k8[2 * pi + 1]) * rk * GK[2 * pi + 1];
    const float kk0 = xr * c - xi * s_ + FB[2 * pi];
    const float kk1 = xr * s_ + xi * c + FB[2 * pi + 1];
    ko[pi] = (unsigned)f2bf(kk0) | ((unsigned)f2bf(kk1) << 16);
    const float v0 = bf2f((u16)v8[2 * pi]) + VF[2 * pi] + VS[2 * pi];
    const float v1 = bf2f((u16)v8[2 * pi + 1]) + VF[2 * pi + 1] + VS[2 * pi + 1];
    vo[pi] = (unsigned)f2bf(v0) | ((unsigned)f2bf(v1) << 16);
  }
  *(uint4*)(Qf + (size_t)s * DIM + d0) = make_uint4(qo[0], qo[1], qo[2], qo[3]);
  *(uint4*)(Kf + (size_t)s * DIM + d0) = make_uint4(ko[0], ko[1], ko[2], ko[3]);
  *(uint4*)(Vf + (size_t)s * DIM + d0) = make_uint4(vo[0], vo[1], vo[2], vo[3]);
}

// ---------------- 6. V transpose: Vf[s][1536] -> Vt[dglob][SPAD] -----------
__global__ __launch_bounds__(256) void k_transpose_v(const u16* __restrict__ Vf,
                                                     u16* __restrict__ Vt) {
  __shared__ u16 tile[64][65];
  const int s0 = blockIdx.x * 64, c0 = blockIdx.y * 64;
  const int c = threadIdx.x & 63, r4 = threadIdx.x >> 6;
#pragma unroll
  for (int rr = 0; rr < 64; rr += 4) {
    const int s = s0 + r4 + rr;
    tile[r4 + rr][c] = (s < SEQ) ? Vf[(size_t)s * DIM + c0 + c] : (u16)0;
  }
  __syncthreads();
#pragma unroll
  for (int rr = 0; rr < 64; rr += 4) {
    const int dglob = c0 + r4 + rr;
    Vt[(size_t)dglob * SPAD + s0 + c] = tile[c][r4 + rr];
  }
}

// ---------------- 7. flash attention: KVBLK=128, per-group pipeline --------
// 1D grid 240: gb = (bid&7)*30 + (bid>>3); h = gb/20, bx = gb%20 (R13:
// FETCH 80->18MB). Fixed-scale softmax is order-free, so each 128-key tile
// is processed as 4 independent 32-key groups: {8 QK MFMA -> exp2/pack ->
// permlane -> 8 PV MFMA}. Halves barrier pairs (98->50) and staging calls
// vs KVBLK=64; only one f32x16 S-block live at a time. PV still accumulates
// key-slices in ascending key order -> bit-identical O.
// K LDS [128 key][16 ch][8] ch^=key&15; V^T LDS [128 d][16 ch][8] ch^=d&15.
// LDS 2x(32+32)KB = 128KB (R6 proved >64KB static works). 320 thr, 5 warps.
__global__ __launch_bounds__(320, 2) void k_attn(const u16* __restrict__ Qf,
                                                 const u16* __restrict__ Kf,
                                                 const u16* __restrict__ Vt,
                                                 u16* __restrict__ AttO) {
  __shared__ short Ks[2][16384];  // [128 key][16 chunk][8]
  __shared__ short Vs[2][16384];  // [128 d][16 chunk][8]
  const int bid = blockIdx.x;
  const int gb = (bid & 7) * 30 + (bid >> 3);
  const int h = gb / 20;
  const int bx = gb - h * 20;
  const int tid = threadIdx.x;
  const int lane = tid & 63, w = tid >> 6;     // w in 0..4
  const int l31 = lane & 31, hi = lane >> 5;
  const int qrow = bx * 160 + w * 32 + l31;

  // Q B-frags: qb[s] = Q[qrow][16s + 8hi + j]
  s16x8 qb[8];
  {
    const u16* qp = Qf + (size_t)qrow * DIM + h * HD + hi * 8;
#pragma unroll
    for (int s = 0; s < 8; ++s) qb[s] = *(const s16x8*)(qp + s * 16);
  }

  f32x16 o[4];
#pragma unroll
  for (int d = 0; d < 4; ++d)
#pragma unroll
    for (int r = 0; r < 16; ++r) o[d][r] = 0.f;
  float sl = 0.f;

  // staging pointers (warps 0..3: each stages 32 K-rows + 32 V-rows)
  const u16* Kp[8];
  const u16* Vp[8];
  if (w < 4) {
#pragma unroll
    for (int it = 0; it < 8; ++it) {
      const int krow = w * 32 + it * 4 + (lane >> 4);
      const int kch = (lane & 15) ^ (krow & 15);
      Kp[it] = Kf + (size_t)krow * DIM + h * HD + kch * 8;
      const int vrow = w * 32 + it * 4 + (lane >> 4);
      const int vch = (lane & 15) ^ (vrow & 15);
      Vp[it] = Vt + (size_t)(h * HD + vrow) * SPAD + vch * 8;
    }
  }
  auto stage = [&](int T, int B) {
    const size_t kof = (size_t)T * KVBLK * DIM;
    const int vof = T * KVBLK;
#pragma unroll
    for (int it = 0; it < 8; ++it) {
      gload16(Kp[it] + kof, &Ks[B][(w * 32 + it * 4) * 128]);
      gload16(Vp[it] + vof, &Vs[B][(w * 32 + it * 4) * 128]);
    }
  };

  if (w < 4) {
    asm volatile("s_waitcnt vmcnt(0)" ::: "memory");
    stage(0, 0);
  }

  for (int t = 0; t < NTILES; ++t) {
    const int b = t & 1;
    if (w < 4) {
      if (t + 1 < NTILES) {
        stage(t + 1, b ^ 1);
        asm volatile("s_waitcnt vmcnt(16)" ::: "memory");  // tile t's 16 done
      } else {
        asm volatile("s_waitcnt vmcnt(0)" ::: "memory");
      }
    }
    __builtin_amdgcn_s_barrier();
    __builtin_amdgcn_sched_barrier(0);

    // 4 independent 32-key groups: QK -> softmax -> PV per group
#pragma unroll
    for (int grp = 0; grp < 4; ++grp) {
      // S^T = K Q  (D[key][q]: col q = l31, row key = grp*32 + CROW(r,hi))
      f32x16 st;
#pragma unroll
      for (int r = 0; r < 16; ++r) st[r] = 0.f;
      __builtin_amdgcn_s_setprio(1);
#pragma unroll
      for (int s = 0; s < 8; ++s) {
        const s16x8 ka = *(const s16x8*)&Ks[b][(grp * 32 + l31) * 128 +
                                              (((2 * s + hi) ^ (lane & 15)) * 8)];
        st = __builtin_amdgcn_mfma_f32_32x32x16_bf16(ka, qb[s], st, 0, 0, 0);
      }
      __builtin_amdgcn_s_setprio(0);

      if (t == NTILES - 1) {  // tile 24: keys >= 3120 invalid
        if (grp == 1) {
#pragma unroll
          for (int r = 8; r < 16; ++r) st[r] = NEGBIG;   // keys 3120..3135
        } else if (grp >= 2) {
#pragma unroll
          for (int r = 0; r < 16; ++r) st[r] = NEGBIG;   // keys 3136..3199
        }
      }
      // P = exp2(S): fixed scale, lane-local sums, pack bf16
      unsigned W[8];
      float p0s = 0.f, p1s = 0.f;
#pragma unroll
      for (int i = 0; i < 8; ++i) {
        const float p0 = exp2f(st[2 * i]);
        const float p1 = exp2f(st[2 * i + 1]);
        p0s += p0; p1s += p1;
        W[i] = cvtpk(p0, p1);
      }
      sl += p0s + p1s;

      // O += P V  (partner exchange via permlane32_swap, VALU not LDS)
      __builtin_amdgcn_s_setprio(1);
#pragma unroll
      for (int s2 = 0; s2 < 2; ++s2) {
        const int S = grp * 2 + s2;        // global key-slice (16 keys)
        unsigned a0 = W[s2 * 4 + 0], b0 = W[s2 * 4 + 2];
        unsigned a1 = W[s2 * 4 + 1], b1 = W[s2 * 4 + 3];
        asm volatile("v_permlane32_swap_b32 %0, %1" : "+v"(a0), "+v"(b0));
        asm volatile("v_permlane32_swap_b32 %0, %1" : "+v"(a1), "+v"(b1));
        unsigned pw[4] = {a0, a1, b0, b1};
        const s16x8 pa = *(const s16x8*)pw;
#pragma unroll
        for (int d = 0; d < 4; ++d) {
          const s16x8 vbf = *(const s16x8*)&Vs[b][(d * 32 + l31) * 128 +
                                                 (((2 * S + hi) ^ (lane & 15)) * 8)];
          o[d] = __builtin_amdgcn_mfma_f32_32x32x16_bf16(pa, vbf, o[d], 0, 0, 0);
        }
      }
      __builtin_amdgcn_s_setprio(0);
    }
    __builtin_amdgcn_s_barrier();
    __builtin_amdgcn_sched_barrier(0);
  }

  sl += __shfl_xor(sl, 32);
  const float rs = 1.0f / sl;
#pragma unroll
  for (int r = 0; r < 16; ++r) {
    const float rq = __shfl(rs, CROW(r, hi));
    const int row = bx * 160 + w * 32 + CROW(r, hi);
    if (row < SEQ) {
#pragma unroll
      for (int d = 0; d < 4; ++d)
        AttO[(size_t)row * DIM + h * HD + d * 32 + l31] = f2bf(o[d][r] * rq);
    }
  }
}

// ---------------------------------------------------------------------------
extern "C" void kernel_launch(void* const* d_in, const int* in_sizes, int n_in,
                              void* d_out, int out_size, void* d_ws, size_t ws_size,
                              hipStream_t stream) {
  const float* x    = (const float*)d_in[0];
  const float* freqs= (const float*)d_in[1];
  const float* Wq   = (const float*)d_in[2];
  const float* bq   = (const float*)d_in[3];
  const float* gq   = (const float*)d_in[4];
  const float* Wk   = (const float*)d_in[5];
  const float* bk   = (const float*)d_in[6];
  const float* gk   = (const float*)d_in[7];
  const float* Wv   = (const float*)d_in[8];
  const float* bv   = (const float*)d_in[9];
  const float* Wo   = (const float*)d_in[10];
  const float* bo   = (const float*)d_in[11];
  const float* qkfb = (const float*)d_in[12];
  const float* vfb  = (const float*)d_in[13];
  const float* vsb  = (const float*)d_in[14];

  if (ws_size < (size_t)87705600) return;

  char* ws = (char*)d_ws;
  u16*   xb    = (u16*)(ws);               // [3200][1536] bf16
  u16*   Vt    = (u16*)(ws);               // alias: xb dead after QKV GEMM
  u16*   WtAll = (u16*)(ws + 9830400);     // [4608][1536] bf16 (Wq|Wk|Wv)^T
  u16*   WoT   = (u16*)(ws + 23986176);    // [1536][1536] bf16 Wo^T
  float* bcat  = (float*)(ws + 28704768);  // [4608]
  u16*   Pqkv  = (u16*)(ws + 28723200);    // [3200][4608] bf16
  u16*   AttO  = (u16*)(ws + 28723200);    // alias: Pqkv dead after k_post
  u16*   Qf    = (u16*)(ws + 58214400);    // [3200][1536] bf16
  u16*   Kf    = (u16*)(ws + 68044800);    // [3200][1536] bf16
  u16*   Vf    = (u16*)(ws + 77875200);    // [3200][1536] bf16

  k_prep<<<7104, 256, 0, stream>>>(x, bq, bk, bv, Wq, Wk, Wv, Wo,
                                   xb, bcat, WtAll, WoT);
  k_gemm<1><<<900, 256, 0, stream>>>(xb, WtAll, bcat, Pqkv, NQKV, DIM, SPAD, 36);
  k_post<<<SEQ, 256, 0, stream>>>(Pqkv, freqs, gq, gk, qkfb, vfb, vsb, Qf, Kf, Vf);
  k_transpose_v<<<dim3(50, 24), 256, 0, stream>>>(Vf, Vt);
  k_attn<<<240, 320, 0, stream>>>(Qf, Kf, Vt, AttO);
  k_gemm<0><<<300, 256, 0, stream>>>(AttO, WoT, bo, d_out, DIM, DIM, SEQ, 12);
}